// Round 5
// baseline (265.540 us; speedup 1.0000x reference)
//
#include <hip/hip_runtime.h>
#include <hip/hip_bf16.h>

#define BATCH 2
#define SEQ 2048
#define DMODEL 1024
#define NHEAD 16
#define DHEAD 64
#define NQKV 3072
#define DINNER 1024

typedef __attribute__((ext_vector_type(4))) short short4v;
typedef __attribute__((ext_vector_type(8))) short short8v;
typedef __attribute__((ext_vector_type(4))) float f32x4;

__device__ __forceinline__ unsigned short f2bf(float f) {
  union { float f; unsigned int u; } c; c.f = f;
  unsigned int u = c.u;
  u += 0x7fffu + ((u >> 16) & 1u);
  return (unsigned short)(u >> 16);
}

__device__ __forceinline__ short8v load_frag(const unsigned short* p0, const unsigned short* p1) {
  union { short8v v8; short4v v4[2]; } u;
  u.v4[0] = *(const short4v*)p0;
  u.v4[1] = *(const short4v*)p1;
  return u.v8;
}

#define GL16(gp, lp)                                             \
  __builtin_amdgcn_global_load_lds(                              \
      (__attribute__((address_space(1))) void*)(gp),             \
      (__attribute__((address_space(3))) void*)(lp), 16, 0, 0)

// ---------------- transpose + cast fp32 [K][N] -> bf16 [N][K] ----------------
__global__ __launch_bounds__(256) void transpose_cast_kernel(const float* __restrict__ in,
                                                             unsigned short* __restrict__ out,
                                                             int K, int N) {
  __shared__ float tile[32][33];
  const int tiles_n = N >> 5;
  const int tn = blockIdx.x % tiles_n;
  const int tk = blockIdx.x / tiles_n;
  const int k0 = tk << 5, n0 = tn << 5;
  const int t = threadIdx.x;
#pragma unroll
  for (int p = 0; p < 4; p++) {
    const int e = p * 256 + t;
    const int r = e >> 5, c = e & 31;
    tile[r][c] = in[(size_t)(k0 + r) * N + n0 + c];
  }
  __syncthreads();
#pragma unroll
  for (int p = 0; p < 4; p++) {
    const int e = p * 256 + t;
    const int r = e >> 5, c = e & 31;
    out[(size_t)(n0 + r) * K + k0 + c] = f2bf(tile[c][r]);
  }
}

// ---------------- RMSNorm (F.normalize * sqrt(dim) * gamma) -> bf16 ----------
__global__ __launch_bounds__(256) void rmsnorm_kernel(const float* __restrict__ x,
                                                      const float* __restrict__ gamma,
                                                      unsigned short* __restrict__ out) {
  const int row = blockIdx.x;
  const int t = threadIdx.x;
  const float* xr = x + (size_t)row * DMODEL;
  float4 v = ((const float4*)xr)[t];
  float ss = v.x * v.x + v.y * v.y + v.z * v.z + v.w * v.w;
#pragma unroll
  for (int off = 1; off < 64; off <<= 1) ss += __shfl_xor(ss, off);
  __shared__ float wss[4];
  if ((t & 63) == 0) wss[t >> 6] = ss;
  __syncthreads();
  const float tot = wss[0] + wss[1] + wss[2] + wss[3];
  float l2 = sqrtf(tot);
  l2 = fmaxf(l2, 1e-12f);
  const float s = 32.0f / l2;  // sqrt(1024)/l2
  const float4 gm = ((const float4*)gamma)[t];
  unsigned short o[4];
  o[0] = f2bf(v.x * s * gm.x);
  o[1] = f2bf(v.y * s * gm.y);
  o[2] = f2bf(v.z * s * gm.z);
  o[3] = f2bf(v.w * s * gm.w);
  unsigned short* op = out + (size_t)row * DMODEL + t * 4;
  *(short4v*)op = *(short4v*)o;
}

// ---------------- shared GEMM core (m97 structure): global_load_lds, linear LDS,
// contiguous 16B fragments (k-slot map = 8g..8g+7, identical for A and B).
#define BM 128
#define BN 128
#define BKT 32

__device__ void gemm_core(const unsigned short* __restrict__ A,
                          const unsigned short* __restrict__ Bt, int K, int rowBase,
                          int colBase, unsigned short* sA, unsigned short* sB,
                          f32x4 acc[4][4]) {
  const int t = threadIdx.x;
  const int lane = t & 63, wave = t >> 6;
  const int l15 = lane & 15, g = lane >> 4;
  const int wr = (wave >> 1) * 64, wc = (wave & 1) * 64;
#pragma unroll
  for (int m = 0; m < 4; m++)
#pragma unroll
    for (int n = 0; n < 4; n++) acc[m][n] = (f32x4){0.f, 0.f, 0.f, 0.f};
  const int r0 = t >> 2, o0 = (t & 3) * 8;
  const unsigned short* Ag0 = A + (size_t)(rowBase + r0) * K + o0;
  const unsigned short* Ag1 = A + (size_t)(rowBase + r0 + 64) * K + o0;
  const unsigned short* Bg0 = Bt + (size_t)(colBase + r0) * K + o0;
  const unsigned short* Bg1 = Bt + (size_t)(colBase + r0 + 64) * K + o0;
  unsigned short* sA0 = sA + t * 8;
  unsigned short* sA1 = sA + (t + 256) * 8;
  unsigned short* sB0 = sB + t * 8;
  unsigned short* sB1 = sB + (t + 256) * 8;
  for (int k0 = 0; k0 < K; k0 += BKT) {
    __syncthreads();
    GL16(Ag0 + k0, sA0);
    GL16(Ag1 + k0, sA1);
    GL16(Bg0 + k0, sB0);
    GL16(Bg1 + k0, sB1);
    asm volatile("s_waitcnt vmcnt(0)" ::: "memory");
    __syncthreads();
    short8v af[4], bf[4];
#pragma unroll
    for (int m = 0; m < 4; m++)
      af[m] = *(const short8v*)(sA + (wr + m * 16 + l15) * BKT + 8 * g);
#pragma unroll
    for (int n = 0; n < 4; n++)
      bf[n] = *(const short8v*)(sB + (wc + n * 16 + l15) * BKT + 8 * g);
#pragma unroll
    for (int m = 0; m < 4; m++)
#pragma unroll
      for (int n = 0; n < 4; n++)
        acc[m][n] = __builtin_amdgcn_mfma_f32_16x16x32_bf16(af[m], bf[n], acc[m][n], 0, 0, 0);
  }
}

// ---------------- QKV GEMM + scatter epilogue (V stored transposed) ----------
__global__ __launch_bounds__(256) void qkv_gemm_kernel(const unsigned short* __restrict__ A,
                                                       const unsigned short* __restrict__ Bt,
                                                       unsigned short* __restrict__ qb,
                                                       unsigned short* __restrict__ kb,
                                                       unsigned short* __restrict__ vtb) {
  __shared__ __align__(16) unsigned short sA[BM * BKT];
  __shared__ __align__(16) unsigned short sB[BN * BKT];
  const int nbn = NQKV / BN;  // 24
  const int bm = blockIdx.x / nbn, bn = blockIdx.x % nbn;
  f32x4 acc[4][4];
  gemm_core(A, Bt, DMODEL, bm * BM, bn * BN, sA, sB, acc);
  const int t = threadIdx.x, lane = t & 63, wave = t >> 6;
  const int l15 = lane & 15, g = lane >> 4;
  const int wr = (wave >> 1) * 64, wc = (wave & 1) * 64;
#pragma unroll
  for (int m = 0; m < 4; m++)
#pragma unroll
    for (int n = 0; n < 4; n++) {
      const int col = bn * BN + wc + n * 16 + l15;
      const int part = col >> 10;
      const int h = (col >> 6) & 15;
      const int d = col & 63;
      const int row0 = bm * BM + wr + m * 16 + 4 * g;
      const int bb = row0 >> 11, i0 = row0 & 2047;
      if (part == 2) {
        // V^T layout: [b*16+h][d][n] -- 4 consecutive i values vectorize
        union { short4v v; unsigned short u[4]; } pk;
#pragma unroll
        for (int r = 0; r < 4; r++) pk.u[r] = f2bf(acc[m][n][r]);
        *(short4v*)(vtb + ((size_t)(bb * NHEAD + h) * DHEAD + d) * SEQ + i0) = pk.v;
      } else {
#pragma unroll
        for (int r = 0; r < 4; r++) {
          const size_t idx = (((size_t)(bb * NHEAD + h)) * SEQ + i0 + r) * DHEAD + d;
          const float v = acc[m][n][r];
          if (part == 0) qb[idx] = f2bf(v * 0.125f);  // q * d^-0.5
          else kb[idx] = f2bf(v);
        }
      }
    }
}

// ---------------- output GEMM: d_out = attn_out @ w_out ----------------------
__global__ __launch_bounds__(256) void out_gemm_kernel(const unsigned short* __restrict__ A,
                                                       const unsigned short* __restrict__ Bt,
                                                       float* __restrict__ C) {
  __shared__ __align__(16) unsigned short sA[BM * BKT];
  __shared__ __align__(16) unsigned short sB[BN * BKT];
  const int nbn = DMODEL / BN;  // 8
  const int bm = blockIdx.x / nbn, bn = blockIdx.x % nbn;
  f32x4 acc[4][4];
  gemm_core(A, Bt, DINNER, bm * BM, bn * BN, sA, sB, acc);
  const int t = threadIdx.x, lane = t & 63, wave = t >> 6;
  const int l15 = lane & 15, g = lane >> 4;
  const int wr = (wave >> 1) * 64, wc = (wave & 1) * 64;
#pragma unroll
  for (int m = 0; m < 4; m++)
#pragma unroll
    for (int n = 0; n < 4; n++) {
      const int col = bn * BN + wc + n * 16 + l15;
#pragma unroll
      for (int r = 0; r < 4; r++) {
        const int row = bm * BM + wr + m * 16 + 4 * g + r;
        C[(size_t)row * DMODEL + col] = acc[m][n][r];
      }
    }
}

// ---------------- causal flash attention: 16-row waves, latency-optimized ----
// 4096 independent waves (4/SIMD resident). Swapped QK^T and swapped PV keep
// softmax state lane-local (col q = l15). Steady-state visit has ZERO cross-
// lane ops: per-lane partial denominator (reduced once at end) + deferred-max
// (rescale only when the row max grows). K double-buffered in regs; V issued
// early each visit (consumed ~300cy later at PV).
__global__ __launch_bounds__(256, 4) void attn_kernel(const unsigned short* __restrict__ qb,
                                                      const unsigned short* __restrict__ kb,
                                                      const unsigned short* __restrict__ vtb,
                                                      unsigned short* __restrict__ ob) {
  const int t = threadIdx.x, lane = t & 63, wave = t >> 6;
  const int l15 = lane & 15, g = lane >> 4;
  const int bh = blockIdx.x & 31;  // b*16+h  (all blocks of a CU share bh -> L2)
  const int p = blockIdx.x >> 5;   // 0..31
  // balanced bijection w(p): per-SIMD visit totals ~constant across the CU set
  const int jj = p & 7, k2 = p >> 3;
  const int w = (k2 == 0) ? 2 * jj : (k2 == 1) ? 31 - 2 * jj
                : (k2 == 2) ? 2 * jj + 1 : 30 - 2 * jj;
  const int tile = wave + 4 * w;  // 0..127
  const int q0 = tile * 16;
  const int qrow = q0 + l15;
  const unsigned short* qptr = qb + (size_t)bh * SEQ * DHEAD;
  const unsigned short* kptr = kb + (size_t)bh * SEQ * DHEAD;
  const unsigned short* vtptr = vtb + (size_t)bh * DHEAD * SEQ;

  // Q fragments (B operand): l15 = q, elems = d (contiguous 8)
  short8v qf[2];
#pragma unroll
  for (int kk = 0; kk < 2; kk++)
    qf[kk] = *(const short8v*)(qptr + (size_t)qrow * DHEAD + kk * 32 + 8 * g);

  float rm = -__builtin_inff();
  float rl = 0.f;          // PER-LANE partial denominator
  f32x4 acc_o[4];          // [df]: col = q = l15, row(4g+r) = d = df*16+4g+r
#pragma unroll
  for (int df = 0; df < 4; df++) acc_o[df] = (f32x4){0.f, 0.f, 0.f, 0.f};

  const int nk = tile / 2 + 1;  // ceil(16*(tile+1)/32)

#define LOADK(kf, kt_)                                                                 \
  do {                                                                                 \
    const int k0_ = (kt_) * 32;                                                        \
    _Pragma("unroll") for (int n = 0; n < 2; n++)                                      \
        _Pragma("unroll") for (int kk = 0; kk < 2; kk++)                               \
            kf[n][kk] = *(const short8v*)(kptr + (size_t)(k0_ + n * 16 + l15) * DHEAD +\
                                          kk * 32 + 8 * g);                            \
  } while (0)

#define STEP(kfC, kfN, kt_, pf_)                                                       \
  do {                                                                                 \
    const int k0_ = (kt_) * 32;                                                        \
    short8v vf_[4]; /* issue V early; consumed at PV after softmax */                  \
    _Pragma("unroll") for (int df = 0; df < 4; df++) {                                 \
      const unsigned short* pv_ = vtptr + (size_t)(df * 16 + l15) * SEQ + k0_ + 4 * g; \
      vf_[df] = load_frag(pv_, pv_ + 16);                                              \
    }                                                                                  \
    f32x4 s_[2];                                                                       \
    s_[0] = (f32x4){0.f, 0.f, 0.f, 0.f};                                               \
    s_[1] = (f32x4){0.f, 0.f, 0.f, 0.f};                                               \
    _Pragma("unroll") for (int n = 0; n < 2; n++)                                      \
        _Pragma("unroll") for (int kk = 0; kk < 2; kk++)                               \
            s_[n] = __builtin_amdgcn_mfma_f32_16x16x32_bf16(kfC[n][kk], qf[kk],        \
                                                            s_[n], 0, 0, 0);           \
    if (pf_) LOADK(kfN, (kt_) + 1);                                                    \
    if ((kt_) == nk - 1) { /* only the diagonal visit masks */                         \
      _Pragma("unroll") for (int n = 0; n < 2; n++)                                    \
          _Pragma("unroll") for (int r = 0; r < 4; r++)                                \
              if (k0_ + n * 16 + 4 * g + r > qrow) s_[n][r] = -__builtin_inff();       \
    }                                                                                  \
    float mx_ = fmaxf(fmaxf(fmaxf(s_[0][0], s_[0][1]), fmaxf(s_[0][2], s_[0][3])),     \
                      fmaxf(fmaxf(s_[1][0], s_[1][1]), fmaxf(s_[1][2], s_[1][3])));    \
    if (!__all(mx_ <= rm)) { /* row max grew: reduce + rescale (rare) */               \
      mx_ = fmaxf(mx_, __shfl_xor(mx_, 16));                                           \
      mx_ = fmaxf(mx_, __shfl_xor(mx_, 32));                                           \
      const float nm_ = fmaxf(rm, mx_);                                                \
      const float al_ = __expf(rm - nm_);                                              \
      rm = nm_;                                                                        \
      rl *= al_;                                                                       \
      _Pragma("unroll") for (int df = 0; df < 4; df++)                                 \
          _Pragma("unroll") for (int r = 0; r < 4; r++) acc_o[df][r] *= al_;           \
    }                                                                                  \
    _Pragma("unroll") for (int n = 0; n < 2; n++)                                      \
        _Pragma("unroll") for (int r = 0; r < 4; r++) {                                \
      const float e_ = __expf(s_[n][r] - rm);                                          \
      s_[n][r] = e_;                                                                   \
      rl += e_;                                                                        \
    }                                                                                  \
    unsigned int pw0_, pw1_, pw2_, pw3_;                                               \
    asm("v_cvt_pk_bf16_f32 %0, %1, %2" : "=v"(pw0_) : "v"(s_[0][0]), "v"(s_[0][1]));   \
    asm("v_cvt_pk_bf16_f32 %0, %1, %2" : "=v"(pw1_) : "v"(s_[0][2]), "v"(s_[0][3]));   \
    asm("v_cvt_pk_bf16_f32 %0, %1, %2" : "=v"(pw2_) : "v"(s_[1][0]), "v"(s_[1][1]));   \
    asm("v_cvt_pk_bf16_f32 %0, %1, %2" : "=v"(pw3_) : "v"(s_[1][2]), "v"(s_[1][3]));   \
    union { short8v v; unsigned int wd[4]; } pa_;                                      \
    pa_.wd[0] = pw0_; pa_.wd[1] = pw1_; pa_.wd[2] = pw2_; pa_.wd[3] = pw3_;            \
    _Pragma("unroll") for (int df = 0; df < 4; df++)                                   \
        acc_o[df] = __builtin_amdgcn_mfma_f32_16x16x32_bf16(vf_[df], pa_.v,            \
                                                            acc_o[df], 0, 0, 0);       \
  } while (0)

  short8v kfA[2][2], kfB[2][2];
  LOADK(kfA, 0);
  int kt = 0;
  for (; kt + 2 <= nk; kt += 2) {
    STEP(kfA, kfB, kt, true);
    STEP(kfB, kfA, kt + 1, kt + 2 < nk);
  }
  if (kt < nk) STEP(kfA, kfB, kt, false);
#undef LOADK
#undef STEP

  // final denominator reduce (once per wave, not per visit)
  float ps = rl;
  ps += __shfl_xor(ps, 16);
  ps += __shfl_xor(ps, 32);
  const float inv = 1.0f / ps;

  // epilogue: ob[b][q][h*64+d] = O * inv ; q = l15 (lane-local)
  const int bb = bh >> 4, hh = bh & 15;
#pragma unroll
  for (int df = 0; df < 4; df++) {
    union { short4v v; unsigned short u[4]; } pk4;
#pragma unroll
    for (int r = 0; r < 4; r++) pk4.u[r] = f2bf(acc_o[df][r] * inv);
    *(short4v*)(ob + ((size_t)bb * SEQ + qrow) * DINNER + hh * DHEAD + df * 16 + 4 * g) =
        pk4.v;
  }
}

extern "C" void kernel_launch(void* const* d_in, const int* in_sizes, int n_in,
                              void* d_out, int out_size, void* d_ws, size_t ws_size,
                              hipStream_t stream) {
  (void)in_sizes; (void)n_in; (void)out_size; (void)ws_size;
  const float* x = (const float*)d_in[0];
  const float* gamma = (const float*)d_in[1];
  const float* w_qkv = (const float*)d_in[2];
  const float* w_out = (const float*)d_in[3];
  float* out = (float*)d_out;
  char* ws = (char*)d_ws;
  unsigned short* wqkvT = (unsigned short*)(ws);                // 6291456 B
  unsigned short* woutT = (unsigned short*)(ws + 6291456);      // 2097152 B
  unsigned short* normed = (unsigned short*)(ws + 8388608);     // 8388608 B
  unsigned short* qbuf = (unsigned short*)(ws + 16777216);      // 8388608 B
  unsigned short* kbuf = (unsigned short*)(ws + 25165824);      // 8388608 B
  unsigned short* vtbuf = (unsigned short*)(ws + 33554432);     // 8388608 B (transposed V)
  unsigned short* aout = (unsigned short*)(ws + 41943040);      // 8388608 B

  hipLaunchKernelGGL(transpose_cast_kernel, dim3((DMODEL / 32) * (NQKV / 32)), dim3(256), 0,
                     stream, w_qkv, wqkvT, DMODEL, NQKV);
  hipLaunchKernelGGL(transpose_cast_kernel, dim3((DINNER / 32) * (DMODEL / 32)), dim3(256), 0,
                     stream, w_out, woutT, DINNER, DMODEL);
  hipLaunchKernelGGL(rmsnorm_kernel, dim3(BATCH * SEQ), dim3(256), 0, stream, x, gamma, normed);
  hipLaunchKernelGGL(qkv_gemm_kernel, dim3((BATCH * SEQ / BM) * (NQKV / BN)), dim3(256), 0,
                     stream, normed, wqkvT, qbuf, kbuf, vtbuf);
  hipLaunchKernelGGL(attn_kernel, dim3(BATCH * NHEAD * 32), dim3(256), 0, stream,
                     qbuf, kbuf, vtbuf, aout);
  hipLaunchKernelGGL(out_gemm_kernel, dim3((BATCH * SEQ / BM) * (DMODEL / BN)), dim3(256), 0,
                     stream, aout, woutT, out);
}

// Round 6
// 189.456 us; speedup vs baseline: 1.4016x; 1.4016x over previous
//
#include <hip/hip_runtime.h>
#include <hip/hip_bf16.h>

#define BATCH 2
#define SEQ 2048
#define DMODEL 1024
#define NHEAD 16
#define DHEAD 64
#define NQKV 3072
#define DINNER 1024

typedef __attribute__((ext_vector_type(4))) short short4v;
typedef __attribute__((ext_vector_type(8))) short short8v;
typedef __attribute__((ext_vector_type(4))) float f32x4;

__device__ __forceinline__ unsigned short f2bf(float f) {
  union { float f; unsigned int u; } c; c.f = f;
  unsigned int u = c.u;
  u += 0x7fffu + ((u >> 16) & 1u);
  return (unsigned short)(u >> 16);
}

__device__ __forceinline__ short8v load_frag(const unsigned short* p0, const unsigned short* p1) {
  union { short8v v8; short4v v4[2]; } u;
  u.v4[0] = *(const short4v*)p0;
  u.v4[1] = *(const short4v*)p1;
  return u.v8;
}

#define GL16(gp, lp)                                             \
  __builtin_amdgcn_global_load_lds(                              \
      (__attribute__((address_space(1))) void*)(gp),             \
      (__attribute__((address_space(3))) void*)(lp), 16, 0, 0)

// ---------------- transpose + cast fp32 [K][N] -> bf16 [N][K] ----------------
__global__ __launch_bounds__(256) void transpose_cast_kernel(const float* __restrict__ in,
                                                             unsigned short* __restrict__ out,
                                                             int K, int N) {
  __shared__ float tile[32][33];
  const int tiles_n = N >> 5;
  const int tn = blockIdx.x % tiles_n;
  const int tk = blockIdx.x / tiles_n;
  const int k0 = tk << 5, n0 = tn << 5;
  const int t = threadIdx.x;
#pragma unroll
  for (int p = 0; p < 4; p++) {
    const int e = p * 256 + t;
    const int r = e >> 5, c = e & 31;
    tile[r][c] = in[(size_t)(k0 + r) * N + n0 + c];
  }
  __syncthreads();
#pragma unroll
  for (int p = 0; p < 4; p++) {
    const int e = p * 256 + t;
    const int r = e >> 5, c = e & 31;
    out[(size_t)(n0 + r) * K + k0 + c] = f2bf(tile[c][r]);
  }
}

// ---------------- RMSNorm (F.normalize * sqrt(dim) * gamma) -> bf16 ----------
__global__ __launch_bounds__(256) void rmsnorm_kernel(const float* __restrict__ x,
                                                      const float* __restrict__ gamma,
                                                      unsigned short* __restrict__ out) {
  const int row = blockIdx.x;
  const int t = threadIdx.x;
  const float* xr = x + (size_t)row * DMODEL;
  float4 v = ((const float4*)xr)[t];
  float ss = v.x * v.x + v.y * v.y + v.z * v.z + v.w * v.w;
#pragma unroll
  for (int off = 1; off < 64; off <<= 1) ss += __shfl_xor(ss, off);
  __shared__ float wss[4];
  if ((t & 63) == 0) wss[t >> 6] = ss;
  __syncthreads();
  const float tot = wss[0] + wss[1] + wss[2] + wss[3];
  float l2 = sqrtf(tot);
  l2 = fmaxf(l2, 1e-12f);
  const float s = 32.0f / l2;  // sqrt(1024)/l2
  const float4 gm = ((const float4*)gamma)[t];
  unsigned short o[4];
  o[0] = f2bf(v.x * s * gm.x);
  o[1] = f2bf(v.y * s * gm.y);
  o[2] = f2bf(v.z * s * gm.z);
  o[3] = f2bf(v.w * s * gm.w);
  unsigned short* op = out + (size_t)row * DMODEL + t * 4;
  *(short4v*)op = *(short4v*)o;
}

// ---------------- shared GEMM core (m97 structure): global_load_lds, linear LDS,
// contiguous 16B fragments (k-slot map = 8g..8g+7, identical for A and B).
#define BM 128
#define BN 128
#define BKT 32

__device__ void gemm_core(const unsigned short* __restrict__ A,
                          const unsigned short* __restrict__ Bt, int K, int rowBase,
                          int colBase, unsigned short* sA, unsigned short* sB,
                          f32x4 acc[4][4]) {
  const int t = threadIdx.x;
  const int lane = t & 63, wave = t >> 6;
  const int l15 = lane & 15, g = lane >> 4;
  const int wr = (wave >> 1) * 64, wc = (wave & 1) * 64;
#pragma unroll
  for (int m = 0; m < 4; m++)
#pragma unroll
    for (int n = 0; n < 4; n++) acc[m][n] = (f32x4){0.f, 0.f, 0.f, 0.f};
  const int r0 = t >> 2, o0 = (t & 3) * 8;
  const unsigned short* Ag0 = A + (size_t)(rowBase + r0) * K + o0;
  const unsigned short* Ag1 = A + (size_t)(rowBase + r0 + 64) * K + o0;
  const unsigned short* Bg0 = Bt + (size_t)(colBase + r0) * K + o0;
  const unsigned short* Bg1 = Bt + (size_t)(colBase + r0 + 64) * K + o0;
  unsigned short* sA0 = sA + t * 8;
  unsigned short* sA1 = sA + (t + 256) * 8;
  unsigned short* sB0 = sB + t * 8;
  unsigned short* sB1 = sB + (t + 256) * 8;
  for (int k0 = 0; k0 < K; k0 += BKT) {
    __syncthreads();
    GL16(Ag0 + k0, sA0);
    GL16(Ag1 + k0, sA1);
    GL16(Bg0 + k0, sB0);
    GL16(Bg1 + k0, sB1);
    asm volatile("s_waitcnt vmcnt(0)" ::: "memory");
    __syncthreads();
    short8v af[4], bf[4];
#pragma unroll
    for (int m = 0; m < 4; m++)
      af[m] = *(const short8v*)(sA + (wr + m * 16 + l15) * BKT + 8 * g);
#pragma unroll
    for (int n = 0; n < 4; n++)
      bf[n] = *(const short8v*)(sB + (wc + n * 16 + l15) * BKT + 8 * g);
#pragma unroll
    for (int m = 0; m < 4; m++)
#pragma unroll
      for (int n = 0; n < 4; n++)
        acc[m][n] = __builtin_amdgcn_mfma_f32_16x16x32_bf16(af[m], bf[n], acc[m][n], 0, 0, 0);
  }
}

// ---------------- QKV GEMM + scatter epilogue (V stored transposed) ----------
__global__ __launch_bounds__(256) void qkv_gemm_kernel(const unsigned short* __restrict__ A,
                                                       const unsigned short* __restrict__ Bt,
                                                       unsigned short* __restrict__ qb,
                                                       unsigned short* __restrict__ kb,
                                                       unsigned short* __restrict__ vtb) {
  __shared__ __align__(16) unsigned short sA[BM * BKT];
  __shared__ __align__(16) unsigned short sB[BN * BKT];
  const int nbn = NQKV / BN;  // 24
  const int bm = blockIdx.x / nbn, bn = blockIdx.x % nbn;
  f32x4 acc[4][4];
  gemm_core(A, Bt, DMODEL, bm * BM, bn * BN, sA, sB, acc);
  const int t = threadIdx.x, lane = t & 63, wave = t >> 6;
  const int l15 = lane & 15, g = lane >> 4;
  const int wr = (wave >> 1) * 64, wc = (wave & 1) * 64;
#pragma unroll
  for (int m = 0; m < 4; m++)
#pragma unroll
    for (int n = 0; n < 4; n++) {
      const int col = bn * BN + wc + n * 16 + l15;
      const int part = col >> 10;
      const int h = (col >> 6) & 15;
      const int d = col & 63;
      const int row0 = bm * BM + wr + m * 16 + 4 * g;
      const int bb = row0 >> 11, i0 = row0 & 2047;
      if (part == 2) {
        // V^T layout: [b*16+h][d][n] -- 4 consecutive i values vectorize
        union { short4v v; unsigned short u[4]; } pk;
#pragma unroll
        for (int r = 0; r < 4; r++) pk.u[r] = f2bf(acc[m][n][r]);
        *(short4v*)(vtb + ((size_t)(bb * NHEAD + h) * DHEAD + d) * SEQ + i0) = pk.v;
      } else {
#pragma unroll
        for (int r = 0; r < 4; r++) {
          const size_t idx = (((size_t)(bb * NHEAD + h)) * SEQ + i0 + r) * DHEAD + d;
          const float v = acc[m][n][r];
          if (part == 0) qb[idx] = f2bf(v * 0.125f);  // q * d^-0.5
          else kb[idx] = f2bf(v);
        }
      }
    }
}

// ---------------- output GEMM: d_out = attn_out @ w_out ----------------------
__global__ __launch_bounds__(256) void out_gemm_kernel(const unsigned short* __restrict__ A,
                                                       const unsigned short* __restrict__ Bt,
                                                       float* __restrict__ C) {
  __shared__ __align__(16) unsigned short sA[BM * BKT];
  __shared__ __align__(16) unsigned short sB[BN * BKT];
  const int nbn = DMODEL / BN;  // 8
  const int bm = blockIdx.x / nbn, bn = blockIdx.x % nbn;
  f32x4 acc[4][4];
  gemm_core(A, Bt, DINNER, bm * BM, bn * BN, sA, sB, acc);
  const int t = threadIdx.x, lane = t & 63, wave = t >> 6;
  const int l15 = lane & 15, g = lane >> 4;
  const int wr = (wave >> 1) * 64, wc = (wave & 1) * 64;
#pragma unroll
  for (int m = 0; m < 4; m++)
#pragma unroll
    for (int n = 0; n < 4; n++) {
      const int col = bn * BN + wc + n * 16 + l15;
#pragma unroll
      for (int r = 0; r < 4; r++) {
        const int row = bm * BM + wr + m * 16 + 4 * g + r;
        C[(size_t)row * DMODEL + col] = acc[m][n][r];
      }
    }
}

// ---------------- causal flash attention: split-K per q-tile -----------------
// One block = one 32-row q-tile; its 4 waves process interleaved k-tiles
// (kt = wave, wave+4, ...) with private flash state (m, l, O), merged once at
// the end via an LDS combine. Uniform short waves (<=17 visits) -> high TLP
// (4 waves/SIMD) with the SAME total visit count as 32-row tiling. Swapped
// QK^T + swapped PV keep softmax state lane-local (col q = l15); steady-state
// visit has zero cross-lane ops (defer-max + per-lane denominator).
__global__ __launch_bounds__(256, 4) void attn_kernel(const unsigned short* __restrict__ qb,
                                                      const unsigned short* __restrict__ kb,
                                                      const unsigned short* __restrict__ vtb,
                                                      unsigned short* __restrict__ ob) {
  __shared__ float sC[4][36][64];  // [wave][32 O + 2 m + 2 l][lane]
  const int t = threadIdx.x, lane = t & 63, wave = t >> 6;
  const int l15 = lane & 15, g = lane >> 4;
  const int bh = blockIdx.x & 31;          // b*16+h
  const int tile = 63 - (blockIdx.x >> 5); // LPT: biggest q-tiles dispatch first
  const int q0 = tile * 32;
  const unsigned short* qptr = qb + (size_t)bh * SEQ * DHEAD;
  const unsigned short* kptr = kb + (size_t)bh * SEQ * DHEAD;
  const unsigned short* vtptr = vtb + (size_t)bh * DHEAD * SEQ;

  // Q fragments (B operand): l15 = q, elems = d (contiguous 8)
  short8v qf[2][2];
#pragma unroll
  for (int qh = 0; qh < 2; qh++)
#pragma unroll
    for (int kk = 0; kk < 2; kk++)
      qf[qh][kk] = *(const short8v*)(qptr + (size_t)(q0 + qh * 16 + l15) * DHEAD +
                                     kk * 32 + 8 * g);

  float rm[2], rl[2];
  f32x4 acc_o[2][4];  // [qh][df]: col = q = l15, row(4g+r) = d = df*16+4g+r
#pragma unroll
  for (int qh = 0; qh < 2; qh++) {
    rm[qh] = -__builtin_inff();
    rl[qh] = 0.f;  // PER-LANE partial denominator
#pragma unroll
    for (int df = 0; df < 4; df++) acc_o[qh][df] = (f32x4){0.f, 0.f, 0.f, 0.f};
  }

  const int nk = tile + 1;
  for (int kt = wave; kt < nk; kt += 4) {
    const int k0 = kt * 32;
    // issue K then V loads up front; QK waits on K, PV on V (arrives early)
    short8v kf[2][2];
#pragma unroll
    for (int n = 0; n < 2; n++)
#pragma unroll
      for (int kk = 0; kk < 2; kk++)
        kf[n][kk] = *(const short8v*)(kptr + (size_t)(k0 + n * 16 + l15) * DHEAD +
                                      kk * 32 + 8 * g);
    short8v vf[4];
#pragma unroll
    for (int df = 0; df < 4; df++) {
      const unsigned short* pv = vtptr + (size_t)(df * 16 + l15) * SEQ + k0 + 4 * g;
      vf[df] = load_frag(pv, pv + 16);
    }
    // QK^T swapped: s[qh][n] = D[key][q], key = k0+n*16+4g+r, q = q0+qh*16+l15
    f32x4 s[2][2];
#pragma unroll
    for (int qh = 0; qh < 2; qh++)
#pragma unroll
      for (int n = 0; n < 2; n++) s[qh][n] = (f32x4){0.f, 0.f, 0.f, 0.f};
#pragma unroll
    for (int qh = 0; qh < 2; qh++)
#pragma unroll
      for (int n = 0; n < 2; n++)
#pragma unroll
        for (int kk = 0; kk < 2; kk++)
          s[qh][n] = __builtin_amdgcn_mfma_f32_16x16x32_bf16(kf[n][kk], qf[qh][kk],
                                                             s[qh][n], 0, 0, 0);
    if (kt == tile) {  // only the diagonal visit masks
#pragma unroll
      for (int qh = 0; qh < 2; qh++) {
        const int qrow = q0 + qh * 16 + l15;
#pragma unroll
        for (int n = 0; n < 2; n++)
#pragma unroll
          for (int r = 0; r < 4; r++)
            if (k0 + n * 16 + 4 * g + r > qrow) s[qh][n][r] = -__builtin_inff();
      }
    }
#pragma unroll
    for (int qh = 0; qh < 2; qh++) {
      float mx = fmaxf(fmaxf(fmaxf(s[qh][0][0], s[qh][0][1]), fmaxf(s[qh][0][2], s[qh][0][3])),
                       fmaxf(fmaxf(s[qh][1][0], s[qh][1][1]), fmaxf(s[qh][1][2], s[qh][1][3])));
      if (!__all(mx <= rm[qh])) {  // row max grew: reduce + rescale (rare)
        mx = fmaxf(mx, __shfl_xor(mx, 16));
        mx = fmaxf(mx, __shfl_xor(mx, 32));
        const float nm = fmaxf(rm[qh], mx);
        const float al = __expf(rm[qh] - nm);
        rm[qh] = nm;
        rl[qh] *= al;
#pragma unroll
        for (int df = 0; df < 4; df++)
#pragma unroll
          for (int r = 0; r < 4; r++) acc_o[qh][df][r] *= al;
      }
#pragma unroll
      for (int n = 0; n < 2; n++)
#pragma unroll
        for (int r = 0; r < 4; r++) {
          const float e = __expf(s[qh][n][r] - rm[qh]);
          s[qh][n][r] = e;
          rl[qh] += e;
        }
    }
#pragma unroll
    for (int qh = 0; qh < 2; qh++) {
      unsigned int pw0, pw1, pw2, pw3;
      asm("v_cvt_pk_bf16_f32 %0, %1, %2" : "=v"(pw0) : "v"(s[qh][0][0]), "v"(s[qh][0][1]));
      asm("v_cvt_pk_bf16_f32 %0, %1, %2" : "=v"(pw1) : "v"(s[qh][0][2]), "v"(s[qh][0][3]));
      asm("v_cvt_pk_bf16_f32 %0, %1, %2" : "=v"(pw2) : "v"(s[qh][1][0]), "v"(s[qh][1][1]));
      asm("v_cvt_pk_bf16_f32 %0, %1, %2" : "=v"(pw3) : "v"(s[qh][1][2]), "v"(s[qh][1][3]));
      union { short8v v; unsigned int wd[4]; } pa;
      pa.wd[0] = pw0; pa.wd[1] = pw1; pa.wd[2] = pw2; pa.wd[3] = pw3;
#pragma unroll
      for (int df = 0; df < 4; df++)
        acc_o[qh][df] = __builtin_amdgcn_mfma_f32_16x16x32_bf16(vf[df], pa.v,
                                                                acc_o[qh][df], 0, 0, 0);
    }
  }

  // finalize this wave's denominators (per q = l15), then publish partials
#pragma unroll
  for (int qh = 0; qh < 2; qh++) {
    float v = rl[qh];
    v += __shfl_xor(v, 16);
    v += __shfl_xor(v, 32);
    rl[qh] = v;
  }
#pragma unroll
  for (int qh = 0; qh < 2; qh++) {
#pragma unroll
    for (int df = 0; df < 4; df++)
#pragma unroll
      for (int r = 0; r < 4; r++)
        sC[wave][qh * 16 + df * 4 + r][lane] = acc_o[qh][df][r];
    sC[wave][32 + qh][lane] = rm[qh];
    sC[wave][34 + qh][lane] = rl[qh];
  }
  __syncthreads();

  // combine: wave handles qh = wave>>1, d-half = wave&1 (8 floats/lane)
  const int cqh = wave >> 1, df0 = (wave & 1) * 2;
  const float m0 = sC[0][32 + cqh][lane], m1 = sC[1][32 + cqh][lane];
  const float m2 = sC[2][32 + cqh][lane], m3 = sC[3][32 + cqh][lane];
  const float M = fmaxf(fmaxf(m0, m1), fmaxf(m2, m3));
  const float w0 = __expf(m0 - M), w1 = __expf(m1 - M);
  const float w2 = __expf(m2 - M), w3 = __expf(m3 - M);
  const float L = w0 * sC[0][34 + cqh][lane] + w1 * sC[1][34 + cqh][lane] +
                  w2 * sC[2][34 + cqh][lane] + w3 * sC[3][34 + cqh][lane];
  const float inv = 1.0f / L;
  const int bb = bh >> 4, hh = bh & 15;
  const int q = q0 + cqh * 16 + l15;
#pragma unroll
  for (int dd = 0; dd < 2; dd++) {
    const int df = df0 + dd;
    union { short4v v; unsigned short u[4]; } pk4;
#pragma unroll
    for (int r = 0; r < 4; r++) {
      const int off = cqh * 16 + df * 4 + r;
      const float O = w0 * sC[0][off][lane] + w1 * sC[1][off][lane] +
                      w2 * sC[2][off][lane] + w3 * sC[3][off][lane];
      pk4.u[r] = f2bf(O * inv);
    }
    *(short4v*)(ob + ((size_t)bb * SEQ + q) * DINNER + hh * DHEAD + df * 16 + 4 * g) =
        pk4.v;
  }
}

extern "C" void kernel_launch(void* const* d_in, const int* in_sizes, int n_in,
                              void* d_out, int out_size, void* d_ws, size_t ws_size,
                              hipStream_t stream) {
  (void)in_sizes; (void)n_in; (void)out_size; (void)ws_size;
  const float* x = (const float*)d_in[0];
  const float* gamma = (const float*)d_in[1];
  const float* w_qkv = (const float*)d_in[2];
  const float* w_out = (const float*)d_in[3];
  float* out = (float*)d_out;
  char* ws = (char*)d_ws;
  unsigned short* wqkvT = (unsigned short*)(ws);                // 6291456 B
  unsigned short* woutT = (unsigned short*)(ws + 6291456);      // 2097152 B
  unsigned short* normed = (unsigned short*)(ws + 8388608);     // 8388608 B
  unsigned short* qbuf = (unsigned short*)(ws + 16777216);      // 8388608 B
  unsigned short* kbuf = (unsigned short*)(ws + 25165824);      // 8388608 B
  unsigned short* vtbuf = (unsigned short*)(ws + 33554432);     // 8388608 B (transposed V)
  unsigned short* aout = (unsigned short*)(ws + 41943040);      // 8388608 B

  hipLaunchKernelGGL(transpose_cast_kernel, dim3((DMODEL / 32) * (NQKV / 32)), dim3(256), 0,
                     stream, w_qkv, wqkvT, DMODEL, NQKV);
  hipLaunchKernelGGL(transpose_cast_kernel, dim3((DINNER / 32) * (DMODEL / 32)), dim3(256), 0,
                     stream, w_out, woutT, DINNER, DMODEL);
  hipLaunchKernelGGL(rmsnorm_kernel, dim3(BATCH * SEQ), dim3(256), 0, stream, x, gamma, normed);
  hipLaunchKernelGGL(qkv_gemm_kernel, dim3((BATCH * SEQ / BM) * (NQKV / BN)), dim3(256), 0,
                     stream, normed, wqkvT, qbuf, kbuf, vtbuf);
  hipLaunchKernelGGL(attn_kernel, dim3(BATCH * NHEAD * 64), dim3(256), 0, stream,
                     qbuf, kbuf, vtbuf, aout);
  hipLaunchKernelGGL(out_gemm_kernel, dim3((BATCH * SEQ / BM) * (DMODEL / BN)), dim3(256), 0,
                     stream, aout, woutT, out);
}

// Round 7
// 167.553 us; speedup vs baseline: 1.5848x; 1.1307x over previous
//
#include <hip/hip_runtime.h>
#include <hip/hip_bf16.h>

#define BATCH 2
#define SEQ 2048
#define DMODEL 1024
#define NHEAD 16
#define DHEAD 64
#define NQKV 3072
#define DINNER 1024

typedef __attribute__((ext_vector_type(4))) short short4v;
typedef __attribute__((ext_vector_type(8))) short short8v;
typedef __attribute__((ext_vector_type(4))) float f32x4;

__device__ __forceinline__ unsigned short f2bf(float f) {
  union { float f; unsigned int u; } c; c.f = f;
  unsigned int u = c.u;
  u += 0x7fffu + ((u >> 16) & 1u);
  return (unsigned short)(u >> 16);
}

__device__ __forceinline__ short8v load_frag(const unsigned short* p0, const unsigned short* p1) {
  union { short8v v8; short4v v4[2]; } u;
  u.v4[0] = *(const short4v*)p0;
  u.v4[1] = *(const short4v*)p1;
  return u.v8;
}

#define GL16(gp, lp)                                             \
  __builtin_amdgcn_global_load_lds(                              \
      (__attribute__((address_space(1))) void*)(gp),             \
      (__attribute__((address_space(3))) void*)(lp), 16, 0, 0)

// ---------------- transpose + cast fp32 [K][N] -> bf16 [N][K] ----------------
__global__ __launch_bounds__(256) void transpose_cast_kernel(const float* __restrict__ in,
                                                             unsigned short* __restrict__ out,
                                                             int K, int N) {
  __shared__ float tile[32][33];
  const int tiles_n = N >> 5;
  const int tn = blockIdx.x % tiles_n;
  const int tk = blockIdx.x / tiles_n;
  const int k0 = tk << 5, n0 = tn << 5;
  const int t = threadIdx.x;
#pragma unroll
  for (int p = 0; p < 4; p++) {
    const int e = p * 256 + t;
    const int r = e >> 5, c = e & 31;
    tile[r][c] = in[(size_t)(k0 + r) * N + n0 + c];
  }
  __syncthreads();
#pragma unroll
  for (int p = 0; p < 4; p++) {
    const int e = p * 256 + t;
    const int r = e >> 5, c = e & 31;
    out[(size_t)(n0 + r) * K + k0 + c] = f2bf(tile[c][r]);
  }
}

// ---------------- RMSNorm (F.normalize * sqrt(dim) * gamma) -> bf16 ----------
__global__ __launch_bounds__(256) void rmsnorm_kernel(const float* __restrict__ x,
                                                      const float* __restrict__ gamma,
                                                      unsigned short* __restrict__ out) {
  const int row = blockIdx.x;
  const int t = threadIdx.x;
  const float* xr = x + (size_t)row * DMODEL;
  float4 v = ((const float4*)xr)[t];
  float ss = v.x * v.x + v.y * v.y + v.z * v.z + v.w * v.w;
#pragma unroll
  for (int off = 1; off < 64; off <<= 1) ss += __shfl_xor(ss, off);
  __shared__ float wss[4];
  if ((t & 63) == 0) wss[t >> 6] = ss;
  __syncthreads();
  const float tot = wss[0] + wss[1] + wss[2] + wss[3];
  float l2 = sqrtf(tot);
  l2 = fmaxf(l2, 1e-12f);
  const float s = 32.0f / l2;  // sqrt(1024)/l2
  const float4 gm = ((const float4*)gamma)[t];
  unsigned short o[4];
  o[0] = f2bf(v.x * s * gm.x);
  o[1] = f2bf(v.y * s * gm.y);
  o[2] = f2bf(v.z * s * gm.z);
  o[3] = f2bf(v.w * s * gm.w);
  unsigned short* op = out + (size_t)row * DMODEL + t * 4;
  *(short4v*)op = *(short4v*)o;
}

// ---------------- shared GEMM core (m97 structure): global_load_lds, linear LDS,
// contiguous 16B fragments (k-slot map = 8g..8g+7, identical for A and B).
#define BM 128
#define BN 128
#define BKT 32

__device__ void gemm_core(const unsigned short* __restrict__ A,
                          const unsigned short* __restrict__ Bt, int K, int rowBase,
                          int colBase, unsigned short* sA, unsigned short* sB,
                          f32x4 acc[4][4]) {
  const int t = threadIdx.x;
  const int lane = t & 63, wave = t >> 6;
  const int l15 = lane & 15, g = lane >> 4;
  const int wr = (wave >> 1) * 64, wc = (wave & 1) * 64;
#pragma unroll
  for (int m = 0; m < 4; m++)
#pragma unroll
    for (int n = 0; n < 4; n++) acc[m][n] = (f32x4){0.f, 0.f, 0.f, 0.f};
  const int r0 = t >> 2, o0 = (t & 3) * 8;
  const unsigned short* Ag0 = A + (size_t)(rowBase + r0) * K + o0;
  const unsigned short* Ag1 = A + (size_t)(rowBase + r0 + 64) * K + o0;
  const unsigned short* Bg0 = Bt + (size_t)(colBase + r0) * K + o0;
  const unsigned short* Bg1 = Bt + (size_t)(colBase + r0 + 64) * K + o0;
  unsigned short* sA0 = sA + t * 8;
  unsigned short* sA1 = sA + (t + 256) * 8;
  unsigned short* sB0 = sB + t * 8;
  unsigned short* sB1 = sB + (t + 256) * 8;
  for (int k0 = 0; k0 < K; k0 += BKT) {
    __syncthreads();
    GL16(Ag0 + k0, sA0);
    GL16(Ag1 + k0, sA1);
    GL16(Bg0 + k0, sB0);
    GL16(Bg1 + k0, sB1);
    asm volatile("s_waitcnt vmcnt(0)" ::: "memory");
    __syncthreads();
    short8v af[4], bf[4];
#pragma unroll
    for (int m = 0; m < 4; m++)
      af[m] = *(const short8v*)(sA + (wr + m * 16 + l15) * BKT + 8 * g);
#pragma unroll
    for (int n = 0; n < 4; n++)
      bf[n] = *(const short8v*)(sB + (wc + n * 16 + l15) * BKT + 8 * g);
#pragma unroll
    for (int m = 0; m < 4; m++)
#pragma unroll
      for (int n = 0; n < 4; n++)
        acc[m][n] = __builtin_amdgcn_mfma_f32_16x16x32_bf16(af[m], bf[n], acc[m][n], 0, 0, 0);
  }
}

// ---------------- QKV GEMM + scatter epilogue (V stored transposed) ----------
__global__ __launch_bounds__(256) void qkv_gemm_kernel(const unsigned short* __restrict__ A,
                                                       const unsigned short* __restrict__ Bt,
                                                       unsigned short* __restrict__ qb,
                                                       unsigned short* __restrict__ kb,
                                                       unsigned short* __restrict__ vtb) {
  __shared__ __align__(16) unsigned short sA[BM * BKT];
  __shared__ __align__(16) unsigned short sB[BN * BKT];
  const int nbn = NQKV / BN;  // 24
  const int bm = blockIdx.x / nbn, bn = blockIdx.x % nbn;
  f32x4 acc[4][4];
  gemm_core(A, Bt, DMODEL, bm * BM, bn * BN, sA, sB, acc);
  const int t = threadIdx.x, lane = t & 63, wave = t >> 6;
  const int l15 = lane & 15, g = lane >> 4;
  const int wr = (wave >> 1) * 64, wc = (wave & 1) * 64;
#pragma unroll
  for (int m = 0; m < 4; m++)
#pragma unroll
    for (int n = 0; n < 4; n++) {
      const int col = bn * BN + wc + n * 16 + l15;
      const int part = col >> 10;
      const int h = (col >> 6) & 15;
      const int d = col & 63;
      const int row0 = bm * BM + wr + m * 16 + 4 * g;
      const int bb = row0 >> 11, i0 = row0 & 2047;
      if (part == 2) {
        // V^T layout: [b*16+h][d][n] -- 4 consecutive i values vectorize
        union { short4v v; unsigned short u[4]; } pk;
#pragma unroll
        for (int r = 0; r < 4; r++) pk.u[r] = f2bf(acc[m][n][r]);
        *(short4v*)(vtb + ((size_t)(bb * NHEAD + h) * DHEAD + d) * SEQ + i0) = pk.v;
      } else {
#pragma unroll
        for (int r = 0; r < 4; r++) {
          const size_t idx = (((size_t)(bb * NHEAD + h)) * SEQ + i0 + r) * DHEAD + d;
          const float v = acc[m][n][r];
          if (part == 0) qb[idx] = f2bf(v * 0.125f);  // q * d^-0.5
          else kb[idx] = f2bf(v);
        }
      }
    }
}

// ---------------- output GEMM: d_out = attn_out @ w_out ----------------------
__global__ __launch_bounds__(256) void out_gemm_kernel(const unsigned short* __restrict__ A,
                                                       const unsigned short* __restrict__ Bt,
                                                       float* __restrict__ C) {
  __shared__ __align__(16) unsigned short sA[BM * BKT];
  __shared__ __align__(16) unsigned short sB[BN * BKT];
  const int nbn = DMODEL / BN;  // 8
  const int bm = blockIdx.x / nbn, bn = blockIdx.x % nbn;
  f32x4 acc[4][4];
  gemm_core(A, Bt, DINNER, bm * BM, bn * BN, sA, sB, acc);
  const int t = threadIdx.x, lane = t & 63, wave = t >> 6;
  const int l15 = lane & 15, g = lane >> 4;
  const int wr = (wave >> 1) * 64, wc = (wave & 1) * 64;
#pragma unroll
  for (int m = 0; m < 4; m++)
#pragma unroll
    for (int n = 0; n < 4; n++) {
      const int col = bn * BN + wc + n * 16 + l15;
#pragma unroll
      for (int r = 0; r < 4; r++) {
        const int row = bm * BM + wr + m * 16 + 4 * g + r;
        C[(size_t)row * DMODEL + col] = acc[m][n][r];
      }
    }
}

// ---------------- causal flash attention: LDS-staged K/V, shared by 4 waves --
// Block = 128 q-rows (4 waves x 32). K/V tiles staged ONCE per block per
// k-tile (4x less L2 traffic than per-wave gathers, dense loads instead of
// strided): K via global_load_lds with both-sides XOR swizzle (inverse-
// permuted global source, swizzled ds_read_b128 -> conflict-free); V^T via
// reg-staging into a padded [64][40] tile. 2-phase pipeline, 1 barrier/tile.
// Softmax: swapped QK/PV keep state lane-local (q = l15); defer-max; per-lane
// partial denominator reduced once at the end.
__global__ __launch_bounds__(256) void attn_kernel(const unsigned short* __restrict__ qb,
                                                   const unsigned short* __restrict__ kb,
                                                   const unsigned short* __restrict__ vtb,
                                                   unsigned short* __restrict__ ob) {
  __shared__ __align__(16) unsigned short sK[2][32 * 64];  // 4KB each, swizzled
  __shared__ __align__(16) unsigned short sV[2][64 * 40];  // padded rows (80B)
  const int t = threadIdx.x, lane = t & 63, wave = t >> 6;
  const int l15 = lane & 15, g = lane >> 4;
  const int bh = blockIdx.x & 31;           // same-bh blocks land on one XCD
  const int qblk = 15 - (blockIdx.x >> 5);  // LPT: biggest q-blocks first
  const int wq0 = qblk * 128 + wave * 32;
  const unsigned short* qptr = qb + (size_t)bh * SEQ * DHEAD;
  const unsigned short* kptr = kb + (size_t)bh * SEQ * DHEAD;
  const unsigned short* vtptr = vtb + (size_t)bh * DHEAD * SEQ;

  // staging geometry (256 threads)
  const int krow = t >> 3, kj = t & 7;           // K: 32 rows x 8 chunks of 16B
  const int ksw = ((kj ^ (krow & 7)) * 8);       // inverse-permuted global src
  const int vrow = t >> 2, vc8 = (t & 3) * 8;    // V: 64 rows x 4 chunks of 16B

  // Q fragments (B operand): l15 = q, elems = d (contiguous 8)
  short8v qf[2][2];
#pragma unroll
  for (int qh = 0; qh < 2; qh++)
#pragma unroll
    for (int kk = 0; kk < 2; kk++)
      qf[qh][kk] = *(const short8v*)(qptr + (size_t)(wq0 + qh * 16 + l15) * DHEAD +
                                     kk * 32 + 8 * g);

  float rm[2], rl[2];
  f32x4 acc_o[2][4];  // [qh][df]: col = q = l15, row(4g+r) = d = df*16+4g+r
#pragma unroll
  for (int qh = 0; qh < 2; qh++) {
    rm[qh] = -__builtin_inff();
    rl[qh] = 0.f;  // per-lane partial denominator
#pragma unroll
    for (int df = 0; df < 4; df++) acc_o[qh][df] = (f32x4){0.f, 0.f, 0.f, 0.f};
  }

  const int nk = 4 * qblk + 4;       // k-tiles this block stages
  const int mylim = 4 * qblk + wave; // last k-tile this wave computes

  // prologue: stage tile 0 into buf 0
  GL16(kptr + (size_t)krow * DHEAD + ksw, sK[0] + t * 8);
  {
    short8v vr = *(const short8v*)(vtptr + (size_t)vrow * SEQ + vc8);
    *(short8v*)(sV[0] + vrow * 40 + vc8) = vr;  // compiler waits vmcnt for vr
  }
  __syncthreads();

  int cur = 0;
  for (int kt = 0; kt < nk; ++kt, cur ^= 1) {
    const int nxt = cur ^ 1;
    const bool more = (kt + 1 < nk);
    short8v vr;
    if (more) {  // issue next tile's loads before compute (latency hides)
      const int k0n = (kt + 1) * 32;
      GL16(kptr + (size_t)(k0n + krow) * DHEAD + ksw, sK[nxt] + t * 8);
      vr = *(const short8v*)(vtptr + (size_t)vrow * SEQ + k0n + vc8);
    }
    if (kt <= mylim) {
      const int k0 = kt * 32;
      const unsigned short* sKc = sK[cur];
      const unsigned short* sVc = sV[cur];
      // K frags from swizzled LDS: data (row, chunk c) at lds row*64+(c^(row&7))*8
      short8v kf[2][2];
#pragma unroll
      for (int n = 0; n < 2; n++) {
        const int row = n * 16 + l15;
#pragma unroll
        for (int kk = 0; kk < 2; kk++)
          kf[n][kk] = *(const short8v*)(sKc + row * 64 + (((kk * 4 + g) ^ (row & 7)) * 8));
      }
      // V frags from padded LDS: row = d = df*16+l15, keys {4g+j, 16+4g+j}
      short8v vf[4];
#pragma unroll
      for (int df = 0; df < 4; df++) {
        const unsigned short* pv = sVc + (df * 16 + l15) * 40 + 4 * g;
        vf[df] = load_frag(pv, pv + 16);
      }
      // QK^T swapped: s[qh][n] = D[key][q]
      f32x4 s[2][2];
#pragma unroll
      for (int qh = 0; qh < 2; qh++)
#pragma unroll
        for (int n = 0; n < 2; n++) s[qh][n] = (f32x4){0.f, 0.f, 0.f, 0.f};
#pragma unroll
      for (int qh = 0; qh < 2; qh++)
#pragma unroll
        for (int n = 0; n < 2; n++)
#pragma unroll
          for (int kk = 0; kk < 2; kk++)
            s[qh][n] = __builtin_amdgcn_mfma_f32_16x16x32_bf16(kf[n][kk], qf[qh][kk],
                                                               s[qh][n], 0, 0, 0);
      if (kt == mylim) {  // diagonal tile: causal mask
#pragma unroll
        for (int qh = 0; qh < 2; qh++) {
          const int qrow = wq0 + qh * 16 + l15;
#pragma unroll
          for (int n = 0; n < 2; n++)
#pragma unroll
            for (int r = 0; r < 4; r++)
              if (k0 + n * 16 + 4 * g + r > qrow) s[qh][n][r] = -__builtin_inff();
        }
      }
#pragma unroll
      for (int qh = 0; qh < 2; qh++) {
        float mx = fmaxf(fmaxf(fmaxf(s[qh][0][0], s[qh][0][1]), fmaxf(s[qh][0][2], s[qh][0][3])),
                         fmaxf(fmaxf(s[qh][1][0], s[qh][1][1]), fmaxf(s[qh][1][2], s[qh][1][3])));
        if (!__all(mx <= rm[qh])) {  // row max grew: reduce + rescale (rare)
          mx = fmaxf(mx, __shfl_xor(mx, 16));
          mx = fmaxf(mx, __shfl_xor(mx, 32));
          const float nm = fmaxf(rm[qh], mx);
          const float al = __expf(rm[qh] - nm);
          rm[qh] = nm;
          rl[qh] *= al;
#pragma unroll
          for (int df = 0; df < 4; df++)
#pragma unroll
            for (int r = 0; r < 4; r++) acc_o[qh][df][r] *= al;
        }
#pragma unroll
        for (int n = 0; n < 2; n++)
#pragma unroll
          for (int r = 0; r < 4; r++) {
            const float e = __expf(s[qh][n][r] - rm[qh]);
            s[qh][n][r] = e;
            rl[qh] += e;
          }
        unsigned int pw0, pw1, pw2, pw3;
        asm("v_cvt_pk_bf16_f32 %0, %1, %2" : "=v"(pw0) : "v"(s[qh][0][0]), "v"(s[qh][0][1]));
        asm("v_cvt_pk_bf16_f32 %0, %1, %2" : "=v"(pw1) : "v"(s[qh][0][2]), "v"(s[qh][0][3]));
        asm("v_cvt_pk_bf16_f32 %0, %1, %2" : "=v"(pw2) : "v"(s[qh][1][0]), "v"(s[qh][1][1]));
        asm("v_cvt_pk_bf16_f32 %0, %1, %2" : "=v"(pw3) : "v"(s[qh][1][2]), "v"(s[qh][1][3]));
        union { short8v v; unsigned int wd[4]; } pa;
        pa.wd[0] = pw0; pa.wd[1] = pw1; pa.wd[2] = pw2; pa.wd[3] = pw3;
#pragma unroll
        for (int df = 0; df < 4; df++)
          acc_o[qh][df] = __builtin_amdgcn_mfma_f32_16x16x32_bf16(vf[df], pa.v,
                                                                  acc_o[qh][df], 0, 0, 0);
      }
    }
    if (more) *(short8v*)(sV[nxt] + vrow * 40 + vc8) = vr;
    __syncthreads();
  }

  // final denominator reduce (once per wave)
  const int bb = bh >> 4, hh = bh & 15;
#pragma unroll
  for (int qh = 0; qh < 2; qh++) {
    float ps = rl[qh];
    ps += __shfl_xor(ps, 16);
    ps += __shfl_xor(ps, 32);
    const float inv = 1.0f / ps;
    const int q = wq0 + qh * 16 + l15;
#pragma unroll
    for (int df = 0; df < 4; df++) {
      union { short4v v; unsigned short u[4]; } pk4;
#pragma unroll
      for (int r = 0; r < 4; r++) pk4.u[r] = f2bf(acc_o[qh][df][r] * inv);
      *(short4v*)(ob + ((size_t)bb * SEQ + q) * DINNER + hh * DHEAD + df * 16 + 4 * g) =
          pk4.v;
    }
  }
}

extern "C" void kernel_launch(void* const* d_in, const int* in_sizes, int n_in,
                              void* d_out, int out_size, void* d_ws, size_t ws_size,
                              hipStream_t stream) {
  (void)in_sizes; (void)n_in; (void)out_size; (void)ws_size;
  const float* x = (const float*)d_in[0];
  const float* gamma = (const float*)d_in[1];
  const float* w_qkv = (const float*)d_in[2];
  const float* w_out = (const float*)d_in[3];
  float* out = (float*)d_out;
  char* ws = (char*)d_ws;
  unsigned short* wqkvT = (unsigned short*)(ws);                // 6291456 B
  unsigned short* woutT = (unsigned short*)(ws + 6291456);      // 2097152 B
  unsigned short* normed = (unsigned short*)(ws + 8388608);     // 8388608 B
  unsigned short* qbuf = (unsigned short*)(ws + 16777216);      // 8388608 B
  unsigned short* kbuf = (unsigned short*)(ws + 25165824);      // 8388608 B
  unsigned short* vtbuf = (unsigned short*)(ws + 33554432);     // 8388608 B (transposed V)
  unsigned short* aout = (unsigned short*)(ws + 41943040);      // 8388608 B

  hipLaunchKernelGGL(transpose_cast_kernel, dim3((DMODEL / 32) * (NQKV / 32)), dim3(256), 0,
                     stream, w_qkv, wqkvT, DMODEL, NQKV);
  hipLaunchKernelGGL(transpose_cast_kernel, dim3((DINNER / 32) * (DMODEL / 32)), dim3(256), 0,
                     stream, w_out, woutT, DINNER, DMODEL);
  hipLaunchKernelGGL(rmsnorm_kernel, dim3(BATCH * SEQ), dim3(256), 0, stream, x, gamma, normed);
  hipLaunchKernelGGL(qkv_gemm_kernel, dim3((BATCH * SEQ / BM) * (NQKV / BN)), dim3(256), 0,
                     stream, normed, wqkvT, qbuf, kbuf, vtbuf);
  hipLaunchKernelGGL(attn_kernel, dim3(BATCH * NHEAD * 16), dim3(256), 0, stream,
                     qbuf, kbuf, vtbuf, aout);
  hipLaunchKernelGGL(out_gemm_kernel, dim3((BATCH * SEQ / BM) * (DMODEL / BN)), dim3(256), 0,
                     stream, aout, woutT, out);
}

// Round 8
// 149.877 us; speedup vs baseline: 1.7717x; 1.1179x over previous
//
#include <hip/hip_runtime.h>
#include <hip/hip_bf16.h>

#define BATCH 2
#define SEQ 2048
#define DMODEL 1024
#define NHEAD 16
#define DHEAD 64
#define NQKV 3072
#define DINNER 1024

typedef __attribute__((ext_vector_type(4))) short short4v;
typedef __attribute__((ext_vector_type(8))) short short8v;
typedef __attribute__((ext_vector_type(4))) float f32x4;

__device__ __forceinline__ unsigned short f2bf(float f) {
  union { float f; unsigned int u; } c; c.f = f;
  unsigned int u = c.u;
  u += 0x7fffu + ((u >> 16) & 1u);
  return (unsigned short)(u >> 16);
}

__device__ __forceinline__ short8v load_frag(const unsigned short* p0, const unsigned short* p1) {
  union { short8v v8; short4v v4[2]; } u;
  u.v4[0] = *(const short4v*)p0;
  u.v4[1] = *(const short4v*)p1;
  return u.v8;
}

#define GL16(gp, lp)                                             \
  __builtin_amdgcn_global_load_lds(                              \
      (__attribute__((address_space(1))) void*)(gp),             \
      (__attribute__((address_space(3))) void*)(lp), 16, 0, 0)

// ---------------- transpose + cast fp32 [K][N] -> bf16 [N][K] ----------------
__global__ __launch_bounds__(256) void transpose_cast_kernel(const float* __restrict__ in,
                                                             unsigned short* __restrict__ out,
                                                             int K, int N) {
  __shared__ float tile[32][33];
  const int tiles_n = N >> 5;
  const int tn = blockIdx.x % tiles_n;
  const int tk = blockIdx.x / tiles_n;
  const int k0 = tk << 5, n0 = tn << 5;
  const int t = threadIdx.x;
#pragma unroll
  for (int p = 0; p < 4; p++) {
    const int e = p * 256 + t;
    const int r = e >> 5, c = e & 31;
    tile[r][c] = in[(size_t)(k0 + r) * N + n0 + c];
  }
  __syncthreads();
#pragma unroll
  for (int p = 0; p < 4; p++) {
    const int e = p * 256 + t;
    const int r = e >> 5, c = e & 31;
    out[(size_t)(n0 + r) * K + k0 + c] = f2bf(tile[c][r]);
  }
}

// ---------------- RMSNorm (F.normalize * sqrt(dim) * gamma) -> bf16 ----------
__global__ __launch_bounds__(256) void rmsnorm_kernel(const float* __restrict__ x,
                                                      const float* __restrict__ gamma,
                                                      unsigned short* __restrict__ out) {
  const int row = blockIdx.x;
  const int t = threadIdx.x;
  const float* xr = x + (size_t)row * DMODEL;
  float4 v = ((const float4*)xr)[t];
  float ss = v.x * v.x + v.y * v.y + v.z * v.z + v.w * v.w;
#pragma unroll
  for (int off = 1; off < 64; off <<= 1) ss += __shfl_xor(ss, off);
  __shared__ float wss[4];
  if ((t & 63) == 0) wss[t >> 6] = ss;
  __syncthreads();
  const float tot = wss[0] + wss[1] + wss[2] + wss[3];
  float l2 = sqrtf(tot);
  l2 = fmaxf(l2, 1e-12f);
  const float s = 32.0f / l2;  // sqrt(1024)/l2
  const float4 gm = ((const float4*)gamma)[t];
  unsigned short o[4];
  o[0] = f2bf(v.x * s * gm.x);
  o[1] = f2bf(v.y * s * gm.y);
  o[2] = f2bf(v.z * s * gm.z);
  o[3] = f2bf(v.w * s * gm.w);
  unsigned short* op = out + (size_t)row * DMODEL + t * 4;
  *(short4v*)op = *(short4v*)o;
}

// ---------------- shared GEMM core (m97 structure): global_load_lds, linear LDS,
// contiguous 16B fragments (k-slot map = 8g..8g+7, identical for A and B).
#define BM 128
#define BN 128
#define BKT 32

__device__ void gemm_core(const unsigned short* __restrict__ A,
                          const unsigned short* __restrict__ Bt, int K, int rowBase,
                          int colBase, unsigned short* sA, unsigned short* sB,
                          f32x4 acc[4][4]) {
  const int t = threadIdx.x;
  const int lane = t & 63, wave = t >> 6;
  const int l15 = lane & 15, g = lane >> 4;
  const int wr = (wave >> 1) * 64, wc = (wave & 1) * 64;
#pragma unroll
  for (int m = 0; m < 4; m++)
#pragma unroll
    for (int n = 0; n < 4; n++) acc[m][n] = (f32x4){0.f, 0.f, 0.f, 0.f};
  const int r0 = t >> 2, o0 = (t & 3) * 8;
  const unsigned short* Ag0 = A + (size_t)(rowBase + r0) * K + o0;
  const unsigned short* Ag1 = A + (size_t)(rowBase + r0 + 64) * K + o0;
  const unsigned short* Bg0 = Bt + (size_t)(colBase + r0) * K + o0;
  const unsigned short* Bg1 = Bt + (size_t)(colBase + r0 + 64) * K + o0;
  unsigned short* sA0 = sA + t * 8;
  unsigned short* sA1 = sA + (t + 256) * 8;
  unsigned short* sB0 = sB + t * 8;
  unsigned short* sB1 = sB + (t + 256) * 8;
  for (int k0 = 0; k0 < K; k0 += BKT) {
    __syncthreads();
    GL16(Ag0 + k0, sA0);
    GL16(Ag1 + k0, sA1);
    GL16(Bg0 + k0, sB0);
    GL16(Bg1 + k0, sB1);
    asm volatile("s_waitcnt vmcnt(0)" ::: "memory");
    __syncthreads();
    short8v af[4], bf[4];
#pragma unroll
    for (int m = 0; m < 4; m++)
      af[m] = *(const short8v*)(sA + (wr + m * 16 + l15) * BKT + 8 * g);
#pragma unroll
    for (int n = 0; n < 4; n++)
      bf[n] = *(const short8v*)(sB + (wc + n * 16 + l15) * BKT + 8 * g);
#pragma unroll
    for (int m = 0; m < 4; m++)
#pragma unroll
      for (int n = 0; n < 4; n++)
        acc[m][n] = __builtin_amdgcn_mfma_f32_16x16x32_bf16(af[m], bf[n], acc[m][n], 0, 0, 0);
  }
}

// ---------------- QKV GEMM + scatter epilogue (V stored transposed) ----------
__global__ __launch_bounds__(256) void qkv_gemm_kernel(const unsigned short* __restrict__ A,
                                                       const unsigned short* __restrict__ Bt,
                                                       unsigned short* __restrict__ qb,
                                                       unsigned short* __restrict__ kb,
                                                       unsigned short* __restrict__ vtb) {
  __shared__ __align__(16) unsigned short sA[BM * BKT];
  __shared__ __align__(16) unsigned short sB[BN * BKT];
  const int nbn = NQKV / BN;  // 24
  const int bm = blockIdx.x / nbn, bn = blockIdx.x % nbn;
  f32x4 acc[4][4];
  gemm_core(A, Bt, DMODEL, bm * BM, bn * BN, sA, sB, acc);
  const int t = threadIdx.x, lane = t & 63, wave = t >> 6;
  const int l15 = lane & 15, g = lane >> 4;
  const int wr = (wave >> 1) * 64, wc = (wave & 1) * 64;
#pragma unroll
  for (int m = 0; m < 4; m++)
#pragma unroll
    for (int n = 0; n < 4; n++) {
      const int col = bn * BN + wc + n * 16 + l15;
      const int part = col >> 10;
      const int h = (col >> 6) & 15;
      const int d = col & 63;
      const int row0 = bm * BM + wr + m * 16 + 4 * g;
      const int bb = row0 >> 11, i0 = row0 & 2047;
      if (part == 2) {
        // V^T layout: [b*16+h][d][n] -- 4 consecutive i values vectorize
        union { short4v v; unsigned short u[4]; } pk;
#pragma unroll
        for (int r = 0; r < 4; r++) pk.u[r] = f2bf(acc[m][n][r]);
        *(short4v*)(vtb + ((size_t)(bb * NHEAD + h) * DHEAD + d) * SEQ + i0) = pk.v;
      } else {
#pragma unroll
        for (int r = 0; r < 4; r++) {
          const size_t idx = (((size_t)(bb * NHEAD + h)) * SEQ + i0 + r) * DHEAD + d;
          const float v = acc[m][n][r];
          if (part == 0) qb[idx] = f2bf(v * 0.125f);  // q * d^-0.5
          else kb[idx] = f2bf(v);
        }
      }
    }
}

// ---------------- output GEMM: d_out = attn_out @ w_out ----------------------
__global__ __launch_bounds__(256) void out_gemm_kernel(const unsigned short* __restrict__ A,
                                                       const unsigned short* __restrict__ Bt,
                                                       float* __restrict__ C) {
  __shared__ __align__(16) unsigned short sA[BM * BKT];
  __shared__ __align__(16) unsigned short sB[BN * BKT];
  const int nbn = DMODEL / BN;  // 8
  const int bm = blockIdx.x / nbn, bn = blockIdx.x % nbn;
  f32x4 acc[4][4];
  gemm_core(A, Bt, DINNER, bm * BM, bn * BN, sA, sB, acc);
  const int t = threadIdx.x, lane = t & 63, wave = t >> 6;
  const int l15 = lane & 15, g = lane >> 4;
  const int wr = (wave >> 1) * 64, wc = (wave & 1) * 64;
#pragma unroll
  for (int m = 0; m < 4; m++)
#pragma unroll
    for (int n = 0; n < 4; n++) {
      const int col = bn * BN + wc + n * 16 + l15;
#pragma unroll
      for (int r = 0; r < 4; r++) {
        const int row = bm * BM + wr + m * 16 + 4 * g + r;
        C[(size_t)row * DMODEL + col] = acc[m][n][r];
      }
    }
}

// ---------------- causal flash attention: LDS-staged, 64 keys per step -------
// Block = 128 q-rows (4 waves x 32). Per barrier step, a 64-key K/V tile is
// staged once for the block (K via global_load_lds + both-sides XOR swizzle;
// V^T reg-staged into a padded [64][72] tile). Halved serial step count vs
// 32-key tiles amortizes per-step fixed latency (barrier drain, ds_read
// latency, serial softmax). Swapped QK/PV keep softmax state lane-local
// (q = l15); defer-max; per-lane partial denominator reduced once at end.
__global__ __launch_bounds__(256) void attn_kernel(const unsigned short* __restrict__ qb,
                                                   const unsigned short* __restrict__ kb,
                                                   const unsigned short* __restrict__ vtb,
                                                   unsigned short* __restrict__ ob) {
  __shared__ __align__(16) unsigned short sK[2][64 * 64];  // 8KB each, swizzled
  __shared__ __align__(16) unsigned short sV[2][64 * 72];  // padded rows (144B)
  const int t = threadIdx.x, lane = t & 63, wave = t >> 6;
  const int l15 = lane & 15, g = lane >> 4;
  const int bh = blockIdx.x & 31;           // same-bh blocks cluster on an XCD
  const int qblk = 15 - (blockIdx.x >> 5);  // LPT: biggest q-blocks first
  const int wq0 = qblk * 128 + wave * 32;
  const unsigned short* qptr = qb + (size_t)bh * SEQ * DHEAD;
  const unsigned short* kptr = kb + (size_t)bh * SEQ * DHEAD;
  const unsigned short* vtptr = vtb + (size_t)bh * DHEAD * SEQ;

  // staging geometry (256 threads, 2 x 16B chunks each for K and V)
  // K tile [64 key][64 d]: chunk c (of 512): row = c>>3, j = c&7; src swizzled
  const int kr0 = t >> 3, kj0 = ((t & 7) ^ (kr0 & 7)) * 8;
  const int kr1 = (t + 256) >> 3, kj1 = ((t & 7) ^ (kr1 & 7)) * 8;
  // V tile [64 d][64 key]: chunk c: row = c>>3, off = (c&7)*8
  const int vr0 = t >> 3, vo0 = (t & 7) * 8;
  const int vr1 = (t + 256) >> 3, vo1 = (t & 7) * 8;

  // Q fragments (B operand): l15 = q, elems = d (contiguous 8)
  short8v qf[2][2];
#pragma unroll
  for (int qh = 0; qh < 2; qh++)
#pragma unroll
    for (int kk = 0; kk < 2; kk++)
      qf[qh][kk] = *(const short8v*)(qptr + (size_t)(wq0 + qh * 16 + l15) * DHEAD +
                                     kk * 32 + 8 * g);

  float rm[2], rl[2];
  f32x4 acc_o[2][4];  // [qh][df]: col = q = l15, row(4g+r) = d = df*16+4g+r
#pragma unroll
  for (int qh = 0; qh < 2; qh++) {
    rm[qh] = -__builtin_inff();
    rl[qh] = 0.f;  // per-lane partial denominator
#pragma unroll
    for (int df = 0; df < 4; df++) acc_o[qh][df] = (f32x4){0.f, 0.f, 0.f, 0.f};
  }

  const int nsteps = 2 * qblk + 2;             // 64-key steps staged
  const int smax = (4 * qblk + wave) >> 1;     // last step this wave computes

  // prologue: stage step 0 into buf 0
  GL16(kptr + (size_t)kr0 * DHEAD + kj0, sK[0] + t * 8);
  GL16(kptr + (size_t)kr1 * DHEAD + kj1, sK[0] + (t + 256) * 8);
  {
    short8v va = *(const short8v*)(vtptr + (size_t)vr0 * SEQ + vo0);
    short8v vb = *(const short8v*)(vtptr + (size_t)vr1 * SEQ + vo1);
    *(short8v*)(sV[0] + vr0 * 72 + vo0) = va;
    *(short8v*)(sV[0] + vr1 * 72 + vo1) = vb;
  }
  __syncthreads();

  int cur = 0;
  for (int s = 0; s < nsteps; ++s, cur ^= 1) {
    const int nxt = cur ^ 1;
    const bool more = (s + 1 < nsteps);
    short8v va, vb;
    if (more) {  // issue next step's loads before compute (latency hides)
      const int k0n = (s + 1) * 64;
      GL16(kptr + (size_t)(k0n + kr0) * DHEAD + kj0, sK[nxt] + t * 8);
      GL16(kptr + (size_t)(k0n + kr1) * DHEAD + kj1, sK[nxt] + (t + 256) * 8);
      va = *(const short8v*)(vtptr + (size_t)vr0 * SEQ + k0n + vo0);
      vb = *(const short8v*)(vtptr + (size_t)vr1 * SEQ + k0n + vo1);
    }
    if (s <= smax) {
      const int k0 = s * 64;
      const unsigned short* sKc = sK[cur];
      const unsigned short* sVc = sV[cur];
      // K frags: n4 = key group (0..3), kk = d half; row = n4*16+l15
      short8v kf[4][2];
#pragma unroll
      for (int n4 = 0; n4 < 4; n4++) {
        const int row = n4 * 16 + l15;
#pragma unroll
        for (int kk = 0; kk < 2; kk++)
          kf[n4][kk] = *(const short8v*)(sKc + row * 64 + (((kk * 4 + g) ^ (row & 7)) * 8));
      }
      // V frags: [ks][df], row = d = df*16+l15, keys ks*32 + {4g+j, 16+4g+j}
      short8v vf[2][4];
#pragma unroll
      for (int ks = 0; ks < 2; ks++)
#pragma unroll
        for (int df = 0; df < 4; df++) {
          const unsigned short* pv = sVc + (df * 16 + l15) * 72 + ks * 32 + 4 * g;
          vf[ks][df] = load_frag(pv, pv + 16);
        }
      const bool diag = (s == smax);
#pragma unroll
      for (int qh = 0; qh < 2; qh++) {
        // QK^T swapped: s4[n4] = D[key][q], key = k0+n4*16+4g+r, q = wq0+qh*16+l15
        f32x4 s4[4];
#pragma unroll
        for (int n4 = 0; n4 < 4; n4++) s4[n4] = (f32x4){0.f, 0.f, 0.f, 0.f};
#pragma unroll
        for (int n4 = 0; n4 < 4; n4++)
#pragma unroll
          for (int kk = 0; kk < 2; kk++)
            s4[n4] = __builtin_amdgcn_mfma_f32_16x16x32_bf16(kf[n4][kk], qf[qh][kk],
                                                             s4[n4], 0, 0, 0);
        if (diag) {  // causal mask (covers the partially/fully masked groups)
          const int qrow = wq0 + qh * 16 + l15;
#pragma unroll
          for (int n4 = 0; n4 < 4; n4++)
#pragma unroll
            for (int r = 0; r < 4; r++)
              if (k0 + n4 * 16 + 4 * g + r > qrow) s4[n4][r] = -__builtin_inff();
        }
        float mx = s4[0][0];
#pragma unroll
        for (int n4 = 0; n4 < 4; n4++)
#pragma unroll
          for (int r = 0; r < 4; r++)
            if (n4 || r) mx = fmaxf(mx, s4[n4][r]);
        if (!__all(mx <= rm[qh])) {  // row max grew: reduce + rescale (rare)
          mx = fmaxf(mx, __shfl_xor(mx, 16));
          mx = fmaxf(mx, __shfl_xor(mx, 32));
          const float nm = fmaxf(rm[qh], mx);
          const float al = __expf(rm[qh] - nm);
          rm[qh] = nm;
          rl[qh] *= al;
#pragma unroll
          for (int df = 0; df < 4; df++)
#pragma unroll
            for (int r = 0; r < 4; r++) acc_o[qh][df][r] *= al;
        }
#pragma unroll
        for (int n4 = 0; n4 < 4; n4++)
#pragma unroll
          for (int r = 0; r < 4; r++) {
            const float e = __expf(s4[n4][r] - rm[qh]);
            s4[n4][r] = e;
            rl[qh] += e;
          }
        unsigned int pw[8];
#pragma unroll
        for (int n4 = 0; n4 < 4; n4++) {
          asm("v_cvt_pk_bf16_f32 %0, %1, %2"
              : "=v"(pw[n4 * 2]) : "v"(s4[n4][0]), "v"(s4[n4][1]));
          asm("v_cvt_pk_bf16_f32 %0, %1, %2"
              : "=v"(pw[n4 * 2 + 1]) : "v"(s4[n4][2]), "v"(s4[n4][3]));
        }
        union { short8v v; unsigned int wd[4]; } paA, paB;
        paA.wd[0] = pw[0]; paA.wd[1] = pw[1]; paA.wd[2] = pw[2]; paA.wd[3] = pw[3];
        paB.wd[0] = pw[4]; paB.wd[1] = pw[5]; paB.wd[2] = pw[6]; paB.wd[3] = pw[7];
#pragma unroll
        for (int df = 0; df < 4; df++) {
          acc_o[qh][df] = __builtin_amdgcn_mfma_f32_16x16x32_bf16(vf[0][df], paA.v,
                                                                  acc_o[qh][df], 0, 0, 0);
          acc_o[qh][df] = __builtin_amdgcn_mfma_f32_16x16x32_bf16(vf[1][df], paB.v,
                                                                  acc_o[qh][df], 0, 0, 0);
        }
      }
    }
    if (more) {
      *(short8v*)(sV[nxt] + vr0 * 72 + vo0) = va;
      *(short8v*)(sV[nxt] + vr1 * 72 + vo1) = vb;
    }
    __syncthreads();
  }

  // final denominator reduce (once per wave) + epilogue
  const int bb = bh >> 4, hh = bh & 15;
#pragma unroll
  for (int qh = 0; qh < 2; qh++) {
    float ps = rl[qh];
    ps += __shfl_xor(ps, 16);
    ps += __shfl_xor(ps, 32);
    const float inv = 1.0f / ps;
    const int q = wq0 + qh * 16 + l15;
#pragma unroll
    for (int df = 0; df < 4; df++) {
      union { short4v v; unsigned short u[4]; } pk4;
#pragma unroll
      for (int r = 0; r < 4; r++) pk4.u[r] = f2bf(acc_o[qh][df][r] * inv);
      *(short4v*)(ob + ((size_t)bb * SEQ + q) * DINNER + hh * DHEAD + df * 16 + 4 * g) =
          pk4.v;
    }
  }
}

extern "C" void kernel_launch(void* const* d_in, const int* in_sizes, int n_in,
                              void* d_out, int out_size, void* d_ws, size_t ws_size,
                              hipStream_t stream) {
  (void)in_sizes; (void)n_in; (void)out_size; (void)ws_size;
  const float* x = (const float*)d_in[0];
  const float* gamma = (const float*)d_in[1];
  const float* w_qkv = (const float*)d_in[2];
  const float* w_out = (const float*)d_in[3];
  float* out = (float*)d_out;
  char* ws = (char*)d_ws;
  unsigned short* wqkvT = (unsigned short*)(ws);                // 6291456 B
  unsigned short* woutT = (unsigned short*)(ws + 6291456);      // 2097152 B
  unsigned short* normed = (unsigned short*)(ws + 8388608);     // 8388608 B
  unsigned short* qbuf = (unsigned short*)(ws + 16777216);      // 8388608 B
  unsigned short* kbuf = (unsigned short*)(ws + 25165824);      // 8388608 B
  unsigned short* vtbuf = (unsigned short*)(ws + 33554432);     // 8388608 B (transposed V)
  unsigned short* aout = (unsigned short*)(ws + 41943040);      // 8388608 B

  hipLaunchKernelGGL(transpose_cast_kernel, dim3((DMODEL / 32) * (NQKV / 32)), dim3(256), 0,
                     stream, w_qkv, wqkvT, DMODEL, NQKV);
  hipLaunchKernelGGL(transpose_cast_kernel, dim3((DINNER / 32) * (DMODEL / 32)), dim3(256), 0,
                     stream, w_out, woutT, DINNER, DMODEL);
  hipLaunchKernelGGL(rmsnorm_kernel, dim3(BATCH * SEQ), dim3(256), 0, stream, x, gamma, normed);
  hipLaunchKernelGGL(qkv_gemm_kernel, dim3((BATCH * SEQ / BM) * (NQKV / BN)), dim3(256), 0,
                     stream, normed, wqkvT, qbuf, kbuf, vtbuf);
  hipLaunchKernelGGL(attn_kernel, dim3(BATCH * NHEAD * 16), dim3(256), 0, stream,
                     qbuf, kbuf, vtbuf, aout);
  hipLaunchKernelGGL(out_gemm_kernel, dim3((BATCH * SEQ / BM) * (DMODEL / BN)), dim3(256), 0,
                     stream, aout, woutT, out);
}

// Round 9
// 112.622 us; speedup vs baseline: 2.3578x; 1.3308x over previous
//
#include <hip/hip_runtime.h>
#include <hip/hip_bf16.h>

#define BATCH 2
#define SEQ 2048
#define DMODEL 1024
#define NHEAD 16
#define DHEAD 64
#define NQKV 3072
#define DINNER 1024

typedef __attribute__((ext_vector_type(4))) short short4v;
typedef __attribute__((ext_vector_type(8))) short short8v;
typedef __attribute__((ext_vector_type(4))) float f32x4;

__device__ __forceinline__ unsigned short f2bf(float f) {
  union { float f; unsigned int u; } c; c.f = f;
  unsigned int u = c.u;
  u += 0x7fffu + ((u >> 16) & 1u);
  return (unsigned short)(u >> 16);
}

__device__ __forceinline__ short8v load_frag(const unsigned short* p0, const unsigned short* p1) {
  union { short8v v8; short4v v4[2]; } u;
  u.v4[0] = *(const short4v*)p0;
  u.v4[1] = *(const short4v*)p1;
  return u.v8;
}

#define GL16(gp, lp)                                             \
  __builtin_amdgcn_global_load_lds(                              \
      (__attribute__((address_space(1))) void*)(gp),             \
      (__attribute__((address_space(3))) void*)(lp), 16, 0, 0)

// ---------------- transpose + cast fp32 [K][N] -> bf16 [N][K] ----------------
__global__ __launch_bounds__(256) void transpose_cast_kernel(const float* __restrict__ in,
                                                             unsigned short* __restrict__ out,
                                                             int K, int N) {
  __shared__ float tile[32][33];
  const int tiles_n = N >> 5;
  const int tn = blockIdx.x % tiles_n;
  const int tk = blockIdx.x / tiles_n;
  const int k0 = tk << 5, n0 = tn << 5;
  const int t = threadIdx.x;
#pragma unroll
  for (int p = 0; p < 4; p++) {
    const int e = p * 256 + t;
    const int r = e >> 5, c = e & 31;
    tile[r][c] = in[(size_t)(k0 + r) * N + n0 + c];
  }
  __syncthreads();
#pragma unroll
  for (int p = 0; p < 4; p++) {
    const int e = p * 256 + t;
    const int r = e >> 5, c = e & 31;
    out[(size_t)(n0 + r) * K + k0 + c] = f2bf(tile[c][r]);
  }
}

// ---------------- RMSNorm (F.normalize * sqrt(dim) * gamma) -> bf16 ----------
__global__ __launch_bounds__(256) void rmsnorm_kernel(const float* __restrict__ x,
                                                      const float* __restrict__ gamma,
                                                      unsigned short* __restrict__ out) {
  const int row = blockIdx.x;
  const int t = threadIdx.x;
  const float* xr = x + (size_t)row * DMODEL;
  float4 v = ((const float4*)xr)[t];
  float ss = v.x * v.x + v.y * v.y + v.z * v.z + v.w * v.w;
#pragma unroll
  for (int off = 1; off < 64; off <<= 1) ss += __shfl_xor(ss, off);
  __shared__ float wss[4];
  if ((t & 63) == 0) wss[t >> 6] = ss;
  __syncthreads();
  const float tot = wss[0] + wss[1] + wss[2] + wss[3];
  float l2 = sqrtf(tot);
  l2 = fmaxf(l2, 1e-12f);
  const float s = 32.0f / l2;  // sqrt(1024)/l2
  const float4 gm = ((const float4*)gamma)[t];
  unsigned short o[4];
  o[0] = f2bf(v.x * s * gm.x);
  o[1] = f2bf(v.y * s * gm.y);
  o[2] = f2bf(v.z * s * gm.z);
  o[3] = f2bf(v.w * s * gm.w);
  unsigned short* op = out + (size_t)row * DMODEL + t * 4;
  *(short4v*)op = *(short4v*)o;
}

// ---------------- shared GEMM core: double-buffered global_load_lds staging --
// Prefetch next k-tile into the other LDS half BEFORE computing the current
// one; single barrier per iteration (its vmcnt-drain completes the prefetch —
// HW-verified semantics from R7/R8). Contiguous 16B fragments.
#define BM 128
#define BN 128
#define BKT 32
#define TILE_E (BM * BKT)

__device__ void gemm_core(const unsigned short* __restrict__ A,
                          const unsigned short* __restrict__ Bt, int K, int rowBase,
                          int colBase, unsigned short* sA, unsigned short* sB,
                          f32x4 acc[4][4]) {
  const int t = threadIdx.x;
  const int lane = t & 63, wave = t >> 6;
  const int l15 = lane & 15, g = lane >> 4;
  const int wr = (wave >> 1) * 64, wc = (wave & 1) * 64;
#pragma unroll
  for (int m = 0; m < 4; m++)
#pragma unroll
    for (int n = 0; n < 4; n++) acc[m][n] = (f32x4){0.f, 0.f, 0.f, 0.f};
  const int r0 = t >> 2, o0 = (t & 3) * 8;
  const unsigned short* Ag0 = A + (size_t)(rowBase + r0) * K + o0;
  const unsigned short* Ag1 = A + (size_t)(rowBase + r0 + 64) * K + o0;
  const unsigned short* Bg0 = Bt + (size_t)(colBase + r0) * K + o0;
  const unsigned short* Bg1 = Bt + (size_t)(colBase + r0 + 64) * K + o0;
  // prologue: tile 0 -> half 0
  GL16(Ag0, sA + t * 8);
  GL16(Ag1, sA + (t + 256) * 8);
  GL16(Bg0, sB + t * 8);
  GL16(Bg1, sB + (t + 256) * 8);
  __syncthreads();  // drains vmcnt -> tile 0 resident
  int cur = 0;
  for (int k0 = 0; k0 < K; k0 += BKT, cur ^= 1) {
    if (k0 + BKT < K) {  // prefetch next tile into the other half
      const int nxto = (cur ^ 1) * TILE_E;
      GL16(Ag0 + k0 + BKT, sA + nxto + t * 8);
      GL16(Ag1 + k0 + BKT, sA + nxto + (t + 256) * 8);
      GL16(Bg0 + k0 + BKT, sB + nxto + t * 8);
      GL16(Bg1 + k0 + BKT, sB + nxto + (t + 256) * 8);
    }
    const unsigned short* sAc = sA + cur * TILE_E;
    const unsigned short* sBc = sB + cur * TILE_E;
    short8v af[4], bf[4];
#pragma unroll
    for (int m = 0; m < 4; m++)
      af[m] = *(const short8v*)(sAc + (wr + m * 16 + l15) * BKT + 8 * g);
#pragma unroll
    for (int n = 0; n < 4; n++)
      bf[n] = *(const short8v*)(sBc + (wc + n * 16 + l15) * BKT + 8 * g);
#pragma unroll
    for (int m = 0; m < 4; m++)
#pragma unroll
      for (int n = 0; n < 4; n++)
        acc[m][n] = __builtin_amdgcn_mfma_f32_16x16x32_bf16(af[m], bf[n], acc[m][n], 0, 0, 0);
    __syncthreads();  // waves done with cur + prefetch complete
  }
}

// ---------------- QKV GEMM + scatter epilogue (V stored transposed) ----------
__global__ __launch_bounds__(256) void qkv_gemm_kernel(const unsigned short* __restrict__ A,
                                                       const unsigned short* __restrict__ Bt,
                                                       unsigned short* __restrict__ qb,
                                                       unsigned short* __restrict__ kb,
                                                       unsigned short* __restrict__ vtb) {
  __shared__ __align__(16) unsigned short sA[2 * TILE_E];
  __shared__ __align__(16) unsigned short sB[2 * TILE_E];
  const int nbn = NQKV / BN;  // 24
  const int bm = blockIdx.x / nbn, bn = blockIdx.x % nbn;
  f32x4 acc[4][4];
  gemm_core(A, Bt, DMODEL, bm * BM, bn * BN, sA, sB, acc);
  const int t = threadIdx.x, lane = t & 63, wave = t >> 6;
  const int l15 = lane & 15, g = lane >> 4;
  const int wr = (wave >> 1) * 64, wc = (wave & 1) * 64;
#pragma unroll
  for (int m = 0; m < 4; m++)
#pragma unroll
    for (int n = 0; n < 4; n++) {
      const int col = bn * BN + wc + n * 16 + l15;
      const int part = col >> 10;
      const int h = (col >> 6) & 15;
      const int d = col & 63;
      const int row0 = bm * BM + wr + m * 16 + 4 * g;
      const int bb = row0 >> 11, i0 = row0 & 2047;
      if (part == 2) {
        // V^T layout: [b*16+h][d][n] -- 4 consecutive i values vectorize
        union { short4v v; unsigned short u[4]; } pk;
#pragma unroll
        for (int r = 0; r < 4; r++) pk.u[r] = f2bf(acc[m][n][r]);
        *(short4v*)(vtb + ((size_t)(bb * NHEAD + h) * DHEAD + d) * SEQ + i0) = pk.v;
      } else {
#pragma unroll
        for (int r = 0; r < 4; r++) {
          const size_t idx = (((size_t)(bb * NHEAD + h)) * SEQ + i0 + r) * DHEAD + d;
          const float v = acc[m][n][r];
          if (part == 0) qb[idx] = f2bf(v * 0.125f);  // q * d^-0.5
          else kb[idx] = f2bf(v);
        }
      }
    }
}

// ---------------- output GEMM: d_out = attn_out @ w_out ----------------------
__global__ __launch_bounds__(256) void out_gemm_kernel(const unsigned short* __restrict__ A,
                                                       const unsigned short* __restrict__ Bt,
                                                       float* __restrict__ C) {
  __shared__ __align__(16) unsigned short sA[2 * TILE_E];
  __shared__ __align__(16) unsigned short sB[2 * TILE_E];
  const int nbn = DMODEL / BN;  // 8
  const int bm = blockIdx.x / nbn, bn = blockIdx.x % nbn;
  f32x4 acc[4][4];
  gemm_core(A, Bt, DINNER, bm * BM, bn * BN, sA, sB, acc);
  const int t = threadIdx.x, lane = t & 63, wave = t >> 6;
  const int l15 = lane & 15, g = lane >> 4;
  const int wr = (wave >> 1) * 64, wc = (wave & 1) * 64;
#pragma unroll
  for (int m = 0; m < 4; m++)
#pragma unroll
    for (int n = 0; n < 4; n++) {
      const int col = bn * BN + wc + n * 16 + l15;
#pragma unroll
      for (int r = 0; r < 4; r++) {
        const int row = bm * BM + wr + m * 16 + 4 * g + r;
        C[(size_t)row * DMODEL + col] = acc[m][n][r];
      }
    }
}

// ---------------- causal flash attention: 64-row blocks, 4 blocks/CU ---------
// Block = 64 q-rows (4 waves x 16). K/V staged once per block per 64-key step
// (K via global_load_lds + both-sides XOR swizzle; V^T reg-staged into padded
// [64][72]). Grid 1024 -> 4 blocks/CU resident (LDS 4x34.8KB = 139KB): four
// INDEPENDENT blocks overlap each other's barrier drains. Constant-sum qblk
// map keeps co-resident step totals ~equal. Swapped QK/PV keep softmax state
// lane-local (q = l15); defer-max; per-lane denominator reduced once at end.
__global__ __launch_bounds__(256, 4) void attn_kernel(const unsigned short* __restrict__ qb,
                                                      const unsigned short* __restrict__ kb,
                                                      const unsigned short* __restrict__ vtb,
                                                      unsigned short* __restrict__ ob) {
  __shared__ __align__(16) unsigned short sK[2][64 * 64];  // 8KB each, swizzled
  __shared__ __align__(16) unsigned short sV[2][64 * 72];  // padded rows (144B)
  const int t = threadIdx.x, lane = t & 63, wave = t >> 6;
  const int l15 = lane & 15, g = lane >> 4;
  const int bh = blockIdx.x & 31;        // low bits -> same-bh blocks same XCD
  const int qord = blockIdx.x >> 5;      // 0..31
  // constant-sum map: co-resident quadruple {q, q+8, q+16, q+24} sums to 62
  const int qblk = (qord < 8) ? 31 - qord
                 : (qord < 16) ? qord - 8
                 : (qord < 24) ? 39 - qord
                 : qord - 16;
  const int qrow = qblk * 64 + wave * 16 + l15;
  const unsigned short* qptr = qb + (size_t)bh * SEQ * DHEAD;
  const unsigned short* kptr = kb + (size_t)bh * SEQ * DHEAD;
  const unsigned short* vtptr = vtb + (size_t)bh * DHEAD * SEQ;

  // staging geometry (256 threads, 2 x 16B chunks each for K and V)
  const int kr0 = t >> 3, kj0 = ((t & 7) ^ (kr0 & 7)) * 8;
  const int kr1 = (t + 256) >> 3, kj1 = ((t & 7) ^ (kr1 & 7)) * 8;
  const int vr0 = t >> 3, vo0 = (t & 7) * 8;
  const int vr1 = (t + 256) >> 3, vo1 = (t & 7) * 8;

  // Q fragments (B operand): l15 = q, elems = d (contiguous 8)
  short8v qf[2];
#pragma unroll
  for (int kk = 0; kk < 2; kk++)
    qf[kk] = *(const short8v*)(qptr + (size_t)qrow * DHEAD + kk * 32 + 8 * g);

  float rm = -__builtin_inff();
  float rl = 0.f;  // per-lane partial denominator
  f32x4 acc_o[4];  // [df]: col = q = l15, row(4g+r) = d = df*16+4g+r
#pragma unroll
  for (int df = 0; df < 4; df++) acc_o[df] = (f32x4){0.f, 0.f, 0.f, 0.f};

  const int nsteps = qblk + 1;  // 64-key steps

  // prologue: stage step 0 into buf 0
  GL16(kptr + (size_t)kr0 * DHEAD + kj0, sK[0] + t * 8);
  GL16(kptr + (size_t)kr1 * DHEAD + kj1, sK[0] + (t + 256) * 8);
  {
    short8v va = *(const short8v*)(vtptr + (size_t)vr0 * SEQ + vo0);
    short8v vb = *(const short8v*)(vtptr + (size_t)vr1 * SEQ + vo1);
    *(short8v*)(sV[0] + vr0 * 72 + vo0) = va;
    *(short8v*)(sV[0] + vr1 * 72 + vo1) = vb;
  }
  __syncthreads();

  int cur = 0;
  for (int s = 0; s < nsteps; ++s, cur ^= 1) {
    const int nxt = cur ^ 1;
    const bool more = (s + 1 < nsteps);
    short8v va, vb;
    if (more) {  // issue next step's loads before compute (latency hides)
      const int k0n = (s + 1) * 64;
      GL16(kptr + (size_t)(k0n + kr0) * DHEAD + kj0, sK[nxt] + t * 8);
      GL16(kptr + (size_t)(k0n + kr1) * DHEAD + kj1, sK[nxt] + (t + 256) * 8);
      va = *(const short8v*)(vtptr + (size_t)vr0 * SEQ + k0n + vo0);
      vb = *(const short8v*)(vtptr + (size_t)vr1 * SEQ + k0n + vo1);
    }
    {
      const int k0 = s * 64;
      const unsigned short* sKc = sK[cur];
      const unsigned short* sVc = sV[cur];
      // K frags: n4 = key group (0..3); row = n4*16+l15 (swizzled read)
      short8v kf[4][2];
#pragma unroll
      for (int n4 = 0; n4 < 4; n4++) {
        const int row = n4 * 16 + l15;
#pragma unroll
        for (int kk = 0; kk < 2; kk++)
          kf[n4][kk] = *(const short8v*)(sKc + row * 64 + (((kk * 4 + g) ^ (row & 7)) * 8));
      }
      // QK^T swapped: s4[n4] = D[key][q], key = k0+n4*16+4g+r, q = qrow = l15
      f32x4 s4[4];
#pragma unroll
      for (int n4 = 0; n4 < 4; n4++) s4[n4] = (f32x4){0.f, 0.f, 0.f, 0.f};
#pragma unroll
      for (int n4 = 0; n4 < 4; n4++)
#pragma unroll
        for (int kk = 0; kk < 2; kk++)
          s4[n4] = __builtin_amdgcn_mfma_f32_16x16x32_bf16(kf[n4][kk], qf[kk],
                                                           s4[n4], 0, 0, 0);
      if (s == nsteps - 1) {  // diagonal step: causal mask
#pragma unroll
        for (int n4 = 0; n4 < 4; n4++)
#pragma unroll
          for (int r = 0; r < 4; r++)
            if (k0 + n4 * 16 + 4 * g + r > qrow) s4[n4][r] = -__builtin_inff();
      }
      float mx = s4[0][0];
#pragma unroll
      for (int n4 = 0; n4 < 4; n4++)
#pragma unroll
        for (int r = 0; r < 4; r++)
          if (n4 || r) mx = fmaxf(mx, s4[n4][r]);
      if (!__all(mx <= rm)) {  // row max grew: reduce + rescale (rare)
        mx = fmaxf(mx, __shfl_xor(mx, 16));
        mx = fmaxf(mx, __shfl_xor(mx, 32));
        const float nm = fmaxf(rm, mx);
        const float al = __expf(rm - nm);
        rm = nm;
        rl *= al;
#pragma unroll
        for (int df = 0; df < 4; df++)
#pragma unroll
          for (int r = 0; r < 4; r++) acc_o[df][r] *= al;
      }
#pragma unroll
      for (int n4 = 0; n4 < 4; n4++)
#pragma unroll
        for (int r = 0; r < 4; r++) {
          const float e = __expf(s4[n4][r] - rm);
          s4[n4][r] = e;
          rl += e;
        }
      unsigned int pw[8];
#pragma unroll
      for (int n4 = 0; n4 < 4; n4++) {
        asm("v_cvt_pk_bf16_f32 %0, %1, %2"
            : "=v"(pw[n4 * 2]) : "v"(s4[n4][0]), "v"(s4[n4][1]));
        asm("v_cvt_pk_bf16_f32 %0, %1, %2"
            : "=v"(pw[n4 * 2 + 1]) : "v"(s4[n4][2]), "v"(s4[n4][3]));
      }
      union { short8v v; unsigned int wd[4]; } paA, paB;
      paA.wd[0] = pw[0]; paA.wd[1] = pw[1]; paA.wd[2] = pw[2]; paA.wd[3] = pw[3];
      paB.wd[0] = pw[4]; paB.wd[1] = pw[5]; paB.wd[2] = pw[6]; paB.wd[3] = pw[7];
      // V frags + PV (vf read after softmax to cap register pressure)
#pragma unroll
      for (int df = 0; df < 4; df++) {
        const unsigned short* pv0 = sVc + (df * 16 + l15) * 72 + 4 * g;
        const short8v vfa = load_frag(pv0, pv0 + 16);
        acc_o[df] = __builtin_amdgcn_mfma_f32_16x16x32_bf16(vfa, paA.v, acc_o[df], 0, 0, 0);
        const unsigned short* pv1 = pv0 + 32;
        const short8v vfb = load_frag(pv1, pv1 + 16);
        acc_o[df] = __builtin_amdgcn_mfma_f32_16x16x32_bf16(vfb, paB.v, acc_o[df], 0, 0, 0);
      }
    }
    if (more) {
      *(short8v*)(sV[nxt] + vr0 * 72 + vo0) = va;
      *(short8v*)(sV[nxt] + vr1 * 72 + vo1) = vb;
    }
    __syncthreads();
  }

  // final denominator reduce (once per wave) + epilogue
  const int bb = bh >> 4, hh = bh & 15;
  float ps = rl;
  ps += __shfl_xor(ps, 16);
  ps += __shfl_xor(ps, 32);
  const float inv = 1.0f / ps;
#pragma unroll
  for (int df = 0; df < 4; df++) {
    union { short4v v; unsigned short u[4]; } pk4;
#pragma unroll
    for (int r = 0; r < 4; r++) pk4.u[r] = f2bf(acc_o[df][r] * inv);
    *(short4v*)(ob + ((size_t)bb * SEQ + qrow) * DINNER + hh * DHEAD + df * 16 + 4 * g) =
        pk4.v;
  }
}

extern "C" void kernel_launch(void* const* d_in, const int* in_sizes, int n_in,
                              void* d_out, int out_size, void* d_ws, size_t ws_size,
                              hipStream_t stream) {
  (void)in_sizes; (void)n_in; (void)out_size; (void)ws_size;
  const float* x = (const float*)d_in[0];
  const float* gamma = (const float*)d_in[1];
  const float* w_qkv = (const float*)d_in[2];
  const float* w_out = (const float*)d_in[3];
  float* out = (float*)d_out;
  char* ws = (char*)d_ws;
  unsigned short* wqkvT = (unsigned short*)(ws);                // 6291456 B
  unsigned short* woutT = (unsigned short*)(ws + 6291456);      // 2097152 B
  unsigned short* normed = (unsigned short*)(ws + 8388608);     // 8388608 B
  unsigned short* qbuf = (unsigned short*)(ws + 16777216);      // 8388608 B
  unsigned short* kbuf = (unsigned short*)(ws + 25165824);      // 8388608 B
  unsigned short* vtbuf = (unsigned short*)(ws + 33554432);     // 8388608 B (transposed V)
  unsigned short* aout = (unsigned short*)(ws + 41943040);      // 8388608 B

  hipLaunchKernelGGL(transpose_cast_kernel, dim3((DMODEL / 32) * (NQKV / 32)), dim3(256), 0,
                     stream, w_qkv, wqkvT, DMODEL, NQKV);
  hipLaunchKernelGGL(transpose_cast_kernel, dim3((DINNER / 32) * (DMODEL / 32)), dim3(256), 0,
                     stream, w_out, woutT, DINNER, DMODEL);
  hipLaunchKernelGGL(rmsnorm_kernel, dim3(BATCH * SEQ), dim3(256), 0, stream, x, gamma, normed);
  hipLaunchKernelGGL(qkv_gemm_kernel, dim3((BATCH * SEQ / BM) * (NQKV / BN)), dim3(256), 0,
                     stream, normed, wqkvT, qbuf, kbuf, vtbuf);
  hipLaunchKernelGGL(attn_kernel, dim3(BATCH * NHEAD * 32), dim3(256), 0, stream,
                     qbuf, kbuf, vtbuf, aout);
  hipLaunchKernelGGL(out_gemm_kernel, dim3((BATCH * SEQ / BM) * (DMODEL / BN)), dim3(256), 0,
                     stream, aout, woutT, out);
}